// Round 2
// baseline (8165.436 us; speedup 1.0000x reference)
//
#include <hip/hip_runtime.h>
#include <hip/hip_bf16.h>

// GraphEncoder: pre-Linear(3->32)+tanh -> GATConv(32->32, skeleton) -> LSTM(768->768, L=256)
// Inputs/outputs fp32. Compute: bf16 MFMA operands, fp32 accum/state.
//
// R5 (v3): v1 persistent structure (192 WG x 256 thr, proven 2290 us) + chain surgery:
//   - spread barrier arrival counters to separate cache lines (cs region reused)
//   - G[t+1] register prefetch issued after h store (cold-HBM off critical path)
//   - counted vmcnt(5) before arrival (retires h store only; out store + G stay in flight)
//   - raw s_barrier (no compiler vmcnt(0) drain)
//   - all 24 h loads issued up front (single exposed MALL latency)
//   - fast sigmoid/tanh via v_exp_f32/v_rcp_f32 (validated in R4: absmax unchanged)
//
// ws layout (bytes):
//   0          Xb      bf16  50331648
//   50331648   WihC    bf16   4718592
//   55050240   WhhC    bf16   4718592
//   59768832   cs      fp32    393216   (legacy: c state | persist: spread barrier barU)
//   60162048   h0      bf16    196608
//   60358656   h1      bf16    196608
//   60555264   smallC  fp32     32768
//   60588032   bar     int       8192   (epoch at [2040])
//   60596224   G       fp32 402653184   (layout [t][128][3072])

#define NB 128
#define LSEQ 256
#define LH 768
#define BGR 32768
#define NWG 96     // legacy path
#define PWG 192    // persistent path: 96 col-groups x 2 row-groups

typedef __attribute__((ext_vector_type(8))) short short8;
typedef __attribute__((ext_vector_type(4))) float floatx4;
typedef __attribute__((ext_vector_type(4))) unsigned int uint4v;
typedef __attribute__((ext_vector_type(2))) unsigned int uint2v;

union frag16 { uint4v u; short8 s; };
union bfbits { __hip_bfloat16 h; unsigned short s; };
union uf2 { uint2v u; float f[2]; };

// fast sigmoid/tanh: v_exp_f32 (2^x) + v_rcp_f32, ~1 ulp (harness-validated R4)
__device__ __forceinline__ float fsig(float x) {
    return __builtin_amdgcn_rcpf(1.f + __builtin_amdgcn_exp2f(-1.44269504f * x));
}
__device__ __forceinline__ float ftanhf(float x) {
    return 1.f - 2.f * __builtin_amdgcn_rcpf(1.f + __builtin_amdgcn_exp2f(2.88539008f * x));
}

// 8 MALL-coherent 16B loads at base + {0..448}
__device__ __forceinline__ void issue8(uint4v* b, const char* base) {
    asm volatile("global_load_dwordx4 %0, %1, off sc0 sc1"            : "=v"(b[0]) : "v"(base));
    asm volatile("global_load_dwordx4 %0, %1, off offset:64 sc0 sc1"  : "=v"(b[1]) : "v"(base));
    asm volatile("global_load_dwordx4 %0, %1, off offset:128 sc0 sc1" : "=v"(b[2]) : "v"(base));
    asm volatile("global_load_dwordx4 %0, %1, off offset:192 sc0 sc1" : "=v"(b[3]) : "v"(base));
    asm volatile("global_load_dwordx4 %0, %1, off offset:256 sc0 sc1" : "=v"(b[4]) : "v"(base));
    asm volatile("global_load_dwordx4 %0, %1, off offset:320 sc0 sc1" : "=v"(b[5]) : "v"(base));
    asm volatile("global_load_dwordx4 %0, %1, off offset:384 sc0 sc1" : "=v"(b[6]) : "v"(base));
    asm volatile("global_load_dwordx4 %0, %1, off offset:448 sc0 sc1" : "=v"(b[7]) : "v"(base));
}
// 4 plain 8B loads: gates I,F,G,O for 2 units (byte offsets 0,3072,6144,9216)
__device__ __forceinline__ void issueG(uint2v* g, const char* gb) {
    const char* gb2 = gb + 6144;
    asm volatile("global_load_dwordx2 %0, %1, off"             : "=v"(g[0]) : "v"(gb));
    asm volatile("global_load_dwordx2 %0, %1, off offset:3072" : "=v"(g[1]) : "v"(gb));
    asm volatile("global_load_dwordx2 %0, %1, off"             : "=v"(g[2]) : "v"(gb2));
    asm volatile("global_load_dwordx2 %0, %1, off offset:3072" : "=v"(g[3]) : "v"(gb2));
}
// counted waits with register ties so consumers cannot be hoisted above them
__device__ __forceinline__ void wait16_touch(uint4v* a, uint2v* g) {
    asm volatile("s_waitcnt vmcnt(16)"
        : "+v"(a[0]), "+v"(a[1]), "+v"(a[2]), "+v"(a[3]),
          "+v"(a[4]), "+v"(a[5]), "+v"(a[6]), "+v"(a[7]),
          "+v"(g[0]), "+v"(g[1]), "+v"(g[2]), "+v"(g[3]) :: "memory");
}
__device__ __forceinline__ void wait8_touch(uint4v* b) {
    asm volatile("s_waitcnt vmcnt(8)"
        : "+v"(b[0]), "+v"(b[1]), "+v"(b[2]), "+v"(b[3]),
          "+v"(b[4]), "+v"(b[5]), "+v"(b[6]), "+v"(b[7]) :: "memory");
}
__device__ __forceinline__ void wait0_touch(uint4v* b) {
    asm volatile("s_waitcnt vmcnt(0)"
        : "+v"(b[0]), "+v"(b[1]), "+v"(b[2]), "+v"(b[3]),
          "+v"(b[4]), "+v"(b[5]), "+v"(b[6]), "+v"(b[7]) :: "memory");
}

// ---------------- Canonicalize weights (fp32 inputs) ----------------
// smallC: W_pre@0(96) b_pre@96(32) W_gat@128(1024) att_src@1152(32)
//         att_dst@1184(32) b_gat@1216(32) b_ih@1248(3072) b_hh@4320(3072)
__global__ __launch_bounds__(256) void convert_kernel(
    const float* W_pre, const float* b_pre, const float* W_gat,
    const float* att_src, const float* att_dst, const float* b_gat,
    const float* W_ih, const float* W_hh, const float* b_ih, const float* b_hh,
    __hip_bfloat16* __restrict__ WihC, __hip_bfloat16* __restrict__ WhhC,
    float* __restrict__ smallC)
{
    long i = (long)blockIdx.x * 256 + threadIdx.x;
    if (i < 2359296) { WihC[i] = __float2bfloat16(W_ih[i]); return; }
    i -= 2359296;
    if (i < 2359296) { WhhC[i] = __float2bfloat16(W_hh[i]); return; }
    i -= 2359296;
    if (i < 96)   { smallC[0 + i]    = W_pre[i];   return; }  i -= 96;
    if (i < 32)   { smallC[96 + i]   = b_pre[i];   return; }  i -= 32;
    if (i < 1024) { smallC[128 + i]  = W_gat[i];   return; }  i -= 1024;
    if (i < 32)   { smallC[1152 + i] = att_src[i]; return; }  i -= 32;
    if (i < 32)   { smallC[1184 + i] = att_dst[i]; return; }  i -= 32;
    if (i < 32)   { smallC[1216 + i] = b_gat[i];   return; }  i -= 32;
    if (i < 3072) { smallC[1248 + i] = b_ih[i];    return; }  i -= 3072;
    if (i < 3072) { smallC[4320 + i] = b_hh[i];    return; }
}

// ---------------- Kernel A: pre + GAT -> Xb (bf16) ----------------
__global__ __launch_bounds__(256) void gat_pre_kernel(
    const float* __restrict__ src,           // [32768][72]
    const float* __restrict__ smallC,
    __hip_bfloat16* __restrict__ Xb)         // [32768][768]
{
    __shared__ float wpre[96];
    __shared__ float bpre[32];
    __shared__ float wgat[1024];
    __shared__ float asrc[32];
    __shared__ float adst[32];
    __shared__ float bgat[32];
    __shared__ float xl[8][72];
    __shared__ float hl[8][24][32];
    __shared__ float xpl[8][24][32];
    __shared__ float asl[8][24];
    __shared__ float adl[8][24];

    const int tid = threadIdx.x;
    for (int i = tid; i < 96; i += 256)   wpre[i] = smallC[i];
    for (int i = tid; i < 1024; i += 256) wgat[i] = smallC[128 + i];
    if (tid < 32) {
        bpre[tid] = smallC[96 + tid];
        asrc[tid] = smallC[1152 + tid];
        adst[tid] = smallC[1184 + tid];
        bgat[tid] = smallC[1216 + tid];
    }

    const int g = tid >> 5;
    const int k = tid & 31;
    const long gb = (long)blockIdx.x * 8 + g;   // graph id = n*256 + t

    for (int i = k; i < 72; i += 32)
        xl[g][i] = src[gb * 72 + i];
    __syncthreads();

    #pragma unroll
    for (int j = 0; j < 24; ++j) {
        float v = xl[g][j*3+0] * wpre[0*32+k]
                + xl[g][j*3+1] * wpre[1*32+k]
                + xl[g][j*3+2] * wpre[2*32+k] + bpre[k];
        hl[g][j][k] = tanhf(v);
    }
    __syncthreads();

    #pragma unroll
    for (int j = 0; j < 24; ++j) {
        float v = 0.f;
        #pragma unroll
        for (int m = 0; m < 32; ++m) v += hl[g][j][m] * wgat[m*32 + k];
        xpl[g][j][k] = v;
    }
    __syncthreads();

    if (k < 24) {
        float vs = 0.f, vd = 0.f;
        #pragma unroll
        for (int m = 0; m < 32; ++m) {
            float x = xpl[g][k][m];
            vs += x * asrc[m];
            vd += x * adst[m];
        }
        asl[g][k] = vs;
        adl[g][k] = vd;
    }
    __syncthreads();

    const int par[24] = {-1,0,0,0,1,2,3,4,5,6,7,8,9,9,9,12,13,14,16,17,18,19,20,21};
    #pragma unroll
    for (int j = 0; j < 24; ++j) {
        int p = par[j];
        float o;
        if (p < 0) {
            o = xpl[g][j][k] + bgat[k];
        } else {
            float es = adl[g][j] + asl[g][j];
            float ep = adl[g][j] + asl[g][p];
            es = es > 0.f ? es : 0.2f * es;
            ep = ep > 0.f ? ep : 0.2f * ep;
            float mx = fmaxf(es, ep);
            float wse = expf(es - mx), wpe = expf(ep - mx);
            float inv = 1.f / (wse + wpe);
            o = (wse * xpl[g][j][k] + wpe * xpl[g][p][k]) * inv + bgat[k];
        }
        Xb[gb * 768 + j * 32 + k] = __float2bfloat16(o);
    }
}

// ---------------- gates_in: G = X @ Wih^T + (b_ih+b_hh), 128x128 tiles ----------------
// grid (256, 24): bx = M-block (rows m*256+t of Xb), by = N-block (wrows).
// G layout [t][128][3072].
__global__ __launch_bounds__(256) void gates_in_kernel(
    const __hip_bfloat16* __restrict__ Xb,   // [32768][768]
    const __hip_bfloat16* __restrict__ Wih,  // [3072][768]
    const float* __restrict__ smallC,
    float* __restrict__ Gf)
{
    const int tid = threadIdx.x;
    const int w = tid >> 6, L = tid & 63;
    const int rh2 = w >> 1, ch2 = w & 1;
    const int q = L >> 4, col16 = L & 15;
    const int R0 = blockIdx.x * 128;
    const int N0 = blockIdx.y * 128;

    const short8* ap[4];
    const short8* bp[4];
    #pragma unroll
    for (int i = 0; i < 4; ++i) {
        ap[i] = (const short8*)(Xb + (size_t)(R0 + 64*rh2 + 16*i + col16) * 768 + q*8);
        bp[i] = (const short8*)(Wih + (size_t)(N0 + 64*ch2 + 16*i + col16) * 768 + q*8);
    }

    floatx4 acc[4][4] = {};
    for (int kk = 0; kk < 24; ++kk) {
        short8 a[4], b[4];
        #pragma unroll
        for (int i = 0; i < 4; ++i) { a[i] = ap[i][kk*4]; b[i] = bp[i][kk*4]; }
        #pragma unroll
        for (int rt = 0; rt < 4; ++rt)
            #pragma unroll
            for (int bt = 0; bt < 4; ++bt)
                acc[rt][bt] = __builtin_amdgcn_mfma_f32_16x16x32_bf16(a[rt], b[bt], acc[rt][bt], 0, 0, 0);
    }

    #pragma unroll
    for (int bt = 0; bt < 4; ++bt) {
        int wrow = N0 + 64*ch2 + 16*bt + col16;
        float bias = smallC[1248 + wrow] + smallC[4320 + wrow];
        #pragma unroll
        for (int rt = 0; rt < 4; ++rt) {
            #pragma unroll
            for (int r = 0; r < 4; ++r) {
                int m_abs = R0 + 64*rh2 + 16*rt + q*4 + r;   // = m*256 + t
                int mm = m_abs >> 8, tt = m_abs & 255;
                size_t idx = ((size_t)tt * 128 + mm) * 3072 + wrow;
                Gf[idx] = acc[rt][bt][r] + bias;
            }
        }
    }
}

// ---------------- Persistent LSTM v3: 192 WGs x 256 thr (v1 base) ----------------
// cg = bx%96 (units cg*8..+7, 32 gate cols), rg = bx/96 (rows rg*64..+63).
// Wave w = 16 rows. Whh slice (48 KB) in LDS. h via sc0/sc1 (MALL-coherent).
// All 24 h loads issued up front; G[t+1] reg-prefetched behind the h store;
// counted vmcnt(5) + raw s_barrier before arrival; spread arrival counters.
__global__ __launch_bounds__(256) void lstm_persist3_kernel(
    const float* __restrict__ G,              // [t][128][3072] fp32
    const __hip_bfloat16* __restrict__ Whh,   // [3072][768]
    __hip_bfloat16* __restrict__ h0g,         // ping-pong h (h0 zeroed)
    __hip_bfloat16* __restrict__ h1g,
    float* __restrict__ out,
    int* __restrict__ bar,                    // epoch at [2040]
    int* __restrict__ barU)                   // spread counters: [(t*8+g)*32], L2 at [t*256+16]
{
    __shared__ short8 whhs[3072];             // [kk][c*4+q] 16B fragments, 48 KB
    __shared__ float gl[64 * 33];             // gate staging, 8448 B

    const int tid = threadIdx.x;
    const int w = tid >> 6;                   // row quarter: rows 16w..16w+15 (local)
    const int L = tid & 63;
    const int q = L >> 4;
    const int col16 = L & 15;
    const int cg = blockIdx.x % 96;
    const int rg = blockIdx.x / 96;

    // ---- stage Whh slice into LDS (once): whhs[f], f=(kk<<7)|(c<<2)|q ----
    for (int b = 0; b < 12; ++b) {
        int f = tid + 256 * b;
        int kk = f >> 7, c = (f >> 2) & 31, qq = f & 3;
        int wrow = 768 * (c >> 3) + cg * 8 + (c & 7);
        whhs[f] = *(const short8*)(Whh + (size_t)wrow * 768 + kk * 32 + qq * 8);
    }
    __syncthreads();                          // drains everything (vmcnt=0 after)

    // epilogue assignment: thread -> (row m_loc, unit pair u2b)
    const int m_loc = tid >> 2;               // 0..63
    const int u2b = (tid & 3) * 2;            // 0,2,4,6
    const int m_glob = rg * 64 + m_loc;
    float creg0 = 0.f, creg1 = 0.f;

    const long rowoff = ((long)((rg * 64 + 16 * w + col16) * 768) + q * 8) * 2;

    // prefetch G[0] (queue: 4 outstanding at loop top)
    uint2v gp[4];
    issueG(gp, (const char*)(G + (size_t)m_glob * 3072 + cg * 8 + u2b));

    for (int t = 0; t < LSEQ; ++t) {
        const char* hr = (const char*)((t & 1) ? h1g : h0g);
        __hip_bfloat16* hw = (t & 1) ? h0g : h1g;
        const char* hbase = hr + rowoff;

        // ---- recurrent GEMM: A = h rows (16/wave) from MALL, B = Whh from LDS ----
        // queue at entry: [G x4, outstore x1] (t>0) or [G x4] (t=0); wave of tid0
        // may have drained during poll — counted waits are upper bounds, still safe.
        floatx4 acc0 = {}, acc1 = {};
        uint4v bufA[8], bufB[8], bufC[8];
        issue8(bufA, hbase);
        issue8(bufB, hbase + 512);
        issue8(bufC, hbase + 1024);

        wait16_touch(bufA, gp);               // retires G, prev out store, bufA
        #pragma unroll
        for (int j = 0; j < 8; ++j) {
            frag16 fu; fu.u = bufA[j];
            short8 bv0 = whhs[j * 128 + (col16 * 4 + q)];
            short8 bv1 = whhs[j * 128 + ((16 + col16) * 4 + q)];
            acc0 = __builtin_amdgcn_mfma_f32_16x16x32_bf16(fu.s, bv0, acc0, 0, 0, 0);
            acc1 = __builtin_amdgcn_mfma_f32_16x16x32_bf16(fu.s, bv1, acc1, 0, 0, 0);
        }
        wait8_touch(bufB);
        #pragma unroll
        for (int j = 0; j < 8; ++j) {
            frag16 fu; fu.u = bufB[j];
            short8 bv0 = whhs[(8 + j) * 128 + (col16 * 4 + q)];
            short8 bv1 = whhs[(8 + j) * 128 + ((16 + col16) * 4 + q)];
            acc0 = __builtin_amdgcn_mfma_f32_16x16x32_bf16(fu.s, bv0, acc0, 0, 0, 0);
            acc1 = __builtin_amdgcn_mfma_f32_16x16x32_bf16(fu.s, bv1, acc1, 0, 0, 0);
        }
        wait0_touch(bufC);
        #pragma unroll
        for (int j = 0; j < 8; ++j) {
            frag16 fu; fu.u = bufC[j];
            short8 bv0 = whhs[(16 + j) * 128 + (col16 * 4 + q)];
            short8 bv1 = whhs[(16 + j) * 128 + ((16 + col16) * 4 + q)];
            acc0 = __builtin_amdgcn_mfma_f32_16x16x32_bf16(fu.s, bv0, acc0, 0, 0, 0);
            acc1 = __builtin_amdgcn_mfma_f32_16x16x32_bf16(fu.s, bv1, acc1, 0, 0, 0);
        }

        // ---- D -> gl: row = 16w + q*4 + r, cols col16 / 16+col16 ----
        #pragma unroll
        for (int r = 0; r < 4; ++r) {
            int mr = 16 * w + q * 4 + r;
            gl[mr * 33 + col16] = acc0[r];
            gl[mr * 33 + 16 + col16] = acc1[r];
        }
        __syncthreads();                      // vmcnt already 0 here — no extra drain

        // ---- elementwise LSTM update (pair of units per thread) ----
        uf2 gI, gF, gGt, gO;
        gI.u = gp[0]; gF.u = gp[1]; gGt.u = gp[2]; gO.u = gp[3];
        float ig0 = gI.f[0] + gl[m_loc * 33 + 0  + u2b];
        float fg0 = gF.f[0] + gl[m_loc * 33 + 8  + u2b];
        float gg0 = gGt.f[0] + gl[m_loc * 33 + 16 + u2b];
        float og0 = gO.f[0] + gl[m_loc * 33 + 24 + u2b];
        float ig1 = gI.f[1] + gl[m_loc * 33 + 0  + u2b + 1];
        float fg1 = gF.f[1] + gl[m_loc * 33 + 8  + u2b + 1];
        float gg1 = gGt.f[1] + gl[m_loc * 33 + 16 + u2b + 1];
        float og1 = gO.f[1] + gl[m_loc * 33 + 24 + u2b + 1];

        float si0 = fsig(ig0), sf0 = fsig(fg0), so0 = fsig(og0);
        float cn0 = sf0 * creg0 + si0 * ftanhf(gg0);
        float hv0 = so0 * ftanhf(cn0);
        creg0 = cn0;
        float si1 = fsig(ig1), sf1 = fsig(fg1), so1 = fsig(og1);
        float cn1 = sf1 * creg1 + si1 * ftanhf(gg1);
        float hv1 = so1 * ftanhf(cn1);
        creg1 = cn1;

        bfbits b0, b1;
        b0.h = __float2bfloat16(hv0);
        b1.h = __float2bfloat16(hv1);
        unsigned hpack = (unsigned)b0.s | ((unsigned)b1.s << 16);
        char* ha = (char*)hw + (size_t)(m_glob * 768 + cg * 8 + u2b) * 2;
        float2 ov; ov.x = hv0; ov.y = hv1;
        float* oa = out + ((size_t)m_glob * 256 + t) * 768 + cg * 8 + u2b;

        if (t < LSEQ - 1) {
            // issue order: h store | G[t+1] x4 | out store  -> vmcnt(5) retires h only
            asm volatile("global_store_dword %0, %1, off sc0 sc1" :: "v"(ha), "v"(hpack) : "memory");
            issueG(gp, (const char*)(G + ((size_t)(t + 1) * 128 + m_glob) * 3072 + cg * 8 + u2b));
            asm volatile("global_store_dwordx2 %0, %1, off" :: "v"(oa), "v"(ov) : "memory");
            asm volatile("s_waitcnt vmcnt(5)" ::: "memory");
            __builtin_amdgcn_s_barrier();     // all waves' h stores at MALL
            if (tid == 0) {
                int g = blockIdx.x & 7;
                int prev = __hip_atomic_fetch_add(&barU[(t * 8 + g) * 32], 1,
                                                  __ATOMIC_RELAXED, __HIP_MEMORY_SCOPE_AGENT);
                bool rel = false;
                if (prev == 23) {                              // 24th of this group
                    int pr = __hip_atomic_fetch_add(&barU[t * 256 + 16], 1,
                                                    __ATOMIC_RELAXED, __HIP_MEMORY_SCOPE_AGENT);
                    if (pr == 7) {                             // 8th group
                        __hip_atomic_store(&bar[2040], t + 1,
                                           __ATOMIC_RELAXED, __HIP_MEMORY_SCOPE_AGENT);
                        rel = true;
                    }
                }
                if (!rel) {
                    while (__hip_atomic_load(&bar[2040], __ATOMIC_RELAXED,
                                             __HIP_MEMORY_SCOPE_AGENT) < t + 1)
                        __builtin_amdgcn_s_sleep(1);
                }
            }
            __builtin_amdgcn_s_barrier();
        } else {
            *(float2*)oa = ov;
            const size_t base = (size_t)NB * LSEQ * LH;
            const size_t ci = (size_t)m_glob * 768 + cg * 8 + u2b;
            float2 hv; hv.x = hv0; hv.y = hv1;
            float2 cv; cv.x = cn0; cv.y = cn1;
            *(float2*)(out + base + ci) = hv;
            *(float2*)(out + base + (size_t)NB * LH + ci) = cv;
        }
    }
}

// ---------------- Legacy per-step path (ws fallback, proven) ----------------
__global__ __launch_bounds__(256) void lstm_step_kernel(
    const __hip_bfloat16* __restrict__ Xb,
    const __hip_bfloat16* __restrict__ Wih,
    const __hip_bfloat16* __restrict__ Whh,
    const float* __restrict__ smallC,
    float* __restrict__ cst,
    const __hip_bfloat16* __restrict__ hr,
    __hip_bfloat16* __restrict__ hw,
    float* __restrict__ out,
    int t)
{
    __shared__ float gls[128 * 33];
    const int tid = threadIdx.x;
    const int w = tid >> 6;
    const int L = tid & 63;
    const int rh = w >> 1;
    const int ct = w & 1;
    const int q = L >> 4;
    const int col16 = L & 15;
    const int c_local = 16 * ct + col16;
    const int gate = c_local >> 3;
    const int uu = c_local & 7;
    const int u = 8 * blockIdx.x + uu;
    const int wrow = 768 * gate + u;

    const short8* bp_i = (const short8*)(Wih + (long)wrow * 768 + q * 8);
    const short8* bp_h = (const short8*)(Whh + (long)wrow * 768 + q * 8);
    const short8* ap_x[4];
    const short8* ap_h[4];
    #pragma unroll
    for (int rt = 0; rt < 4; ++rt) {
        int m = 64 * rh + 16 * rt + col16;
        ap_x[rt] = (const short8*)(Xb + ((long)m * LSEQ + t) * 768 + q * 8);
        ap_h[rt] = (const short8*)(hr + (long)m * 768 + q * 8);
    }
    floatx4 acc[4] = {};
    for (int kk = 0; kk < 768; kk += 32) {
        short8 bv = bp_i[kk >> 3];
        #pragma unroll
        for (int rt = 0; rt < 4; ++rt)
            acc[rt] = __builtin_amdgcn_mfma_f32_16x16x32_bf16(ap_x[rt][kk >> 3], bv, acc[rt], 0, 0, 0);
    }
    for (int kk = 0; kk < 768; kk += 32) {
        short8 bv = bp_h[kk >> 3];
        #pragma unroll
        for (int rt = 0; rt < 4; ++rt)
            acc[rt] = __builtin_amdgcn_mfma_f32_16x16x32_bf16(ap_h[rt][kk >> 3], bv, acc[rt], 0, 0, 0);
    }
    float bias = smallC[1248 + wrow] + smallC[4320 + wrow];
    #pragma unroll
    for (int rt = 0; rt < 4; ++rt)
        #pragma unroll
        for (int r = 0; r < 4; ++r) {
            int m = 64 * rh + 16 * rt + q * 4 + r;
            gls[m * 33 + c_local] = acc[rt][r] + bias;
        }
    __syncthreads();
    for (int item = tid; item < 1024; item += 256) {
        int m = item >> 3;
        int u2l = item & 7;
        float ig = gls[m * 33 + 0  + u2l];
        float fg = gls[m * 33 + 8  + u2l];
        float gg = gls[m * 33 + 16 + u2l];
        float og = gls[m * 33 + 24 + u2l];
        int u2 = 8 * blockIdx.x + u2l;
        int ci = m * 768 + u2;
        float co = cst[ci];
        float si = 1.f / (1.f + expf(-ig));
        float sf = 1.f / (1.f + expf(-fg));
        float so = 1.f / (1.f + expf(-og));
        float cn = sf * co + si * tanhf(gg);
        float h = so * tanhf(cn);
        cst[ci] = cn;
        hw[ci] = __float2bfloat16(h);
        out[((long)m * LSEQ + t) * 768 + u2] = h;
    }
}

__global__ __launch_bounds__(256) void finalize_kernel(
    const __hip_bfloat16* __restrict__ hfin,
    const float* __restrict__ cst,
    float* __restrict__ out)
{
    int i = blockIdx.x * 256 + threadIdx.x;
    const long base = (long)NB * LSEQ * LH;
    out[base + i] = __bfloat162float(hfin[i]);
    out[base + NB * LH + i] = cst[i];
}

extern "C" void kernel_launch(void* const* d_in, const int* in_sizes, int n_in,
                              void* d_out, int out_size, void* d_ws, size_t ws_size,
                              hipStream_t stream) {
    const float* src     = (const float*)d_in[0];
    const float* W_pre   = (const float*)d_in[1];
    const float* b_pre   = (const float*)d_in[2];
    const float* W_gat   = (const float*)d_in[3];
    const float* att_src = (const float*)d_in[4];
    const float* att_dst = (const float*)d_in[5];
    const float* b_gat   = (const float*)d_in[6];
    const float* W_ih    = (const float*)d_in[7];
    const float* W_hh    = (const float*)d_in[8];
    const float* b_ih    = (const float*)d_in[9];
    const float* b_hh    = (const float*)d_in[10];

    float* out = (float*)d_out;
    char* ws = (char*)d_ws;

    __hip_bfloat16* Xb     = (__hip_bfloat16*)(ws);
    __hip_bfloat16* WihC   = (__hip_bfloat16*)(ws + 50331648);
    __hip_bfloat16* WhhC   = (__hip_bfloat16*)(ws + 55050240);
    float*          cs     = (float*)         (ws + 59768832);
    __hip_bfloat16* h0     = (__hip_bfloat16*)(ws + 60162048);
    __hip_bfloat16* h1     = (__hip_bfloat16*)(ws + 60358656);
    float*          smallC = (float*)         (ws + 60555264);
    int*            bar    = (int*)           (ws + 60588032);
    float*          Gin    = (float*)         (ws + 60596224);

    const size_t need_f32 = 60596224 + (size_t)BGR * 3072 * 4;   // ~463 MB
    const int use_persist = (ws_size >= need_f32);

    hipMemsetAsync(h0, 0, NB * LH * sizeof(__hip_bfloat16), stream);

    const long conv_total = 2359296L * 2 + 7392;
    convert_kernel<<<(int)((conv_total + 255) / 256), 256, 0, stream>>>(
        W_pre, b_pre, W_gat, att_src, att_dst, b_gat,
        W_ih, W_hh, b_ih, b_hh, WihC, WhhC, smallC);

    gat_pre_kernel<<<BGR / 8, 256, 0, stream>>>(src, smallC, Xb);

    if (use_persist) {
        hipMemsetAsync(bar, 0, 8192, stream);
        hipMemsetAsync(cs, 0, 262144, stream);   // spread arrival counters (barU)
        dim3 ggrid(256, 24);
        gates_in_kernel<<<ggrid, 256, 0, stream>>>(Xb, WihC, smallC, Gin);
        lstm_persist3_kernel<<<PWG, 256, 0, stream>>>(Gin, WhhC, h0, h1, out,
                                                      bar, (int*)cs);
    } else {
        hipMemsetAsync(cs, 0, NB * LH * sizeof(float), stream);
        __hip_bfloat16* hp[2] = {h0, h1};
        for (int t = 0; t < LSEQ; ++t) {
            lstm_step_kernel<<<NWG, 256, 0, stream>>>(Xb, WihC, WhhC, smallC,
                                                      cs, hp[t & 1], hp[(t + 1) & 1],
                                                      out, t);
        }
        finalize_kernel<<<NB * LH / 256, 256, 0, stream>>>(h0, cs, out);
    }
}

// Round 3
// 2669.556 us; speedup vs baseline: 3.0587x; 3.0587x over previous
//
#include <hip/hip_runtime.h>
#include <hip/hip_bf16.h>

// GraphEncoder: pre-Linear(3->32)+tanh -> GATConv(32->32, skeleton) -> LSTM(768->768, L=256)
// Inputs/outputs fp32 (proven R1->R3). Compute: bf16 MFMA operands, fp32 accum/state.
//
// R6 (v4): exact v1 baseline (proven 3080 us total / 2290 us LSTM) + ONE change:
//   barrier arrival counters spread to separate 128 B cache lines (barU in the
//   idle cs region) to kill same-line agent-atomic serialization (192 RMWs/step
//   on one line in v1). Everything else byte-identical to v1.
//
// ws layout (bytes):
//   0          Xb      bf16  50331648
//   50331648   WihC    bf16   4718592
//   55050240   WhhC    bf16   4718592
//   59768832   cs      fp32    393216   (legacy: c state | persist: spread barU)
//   60162048   h0      bf16    196608
//   60358656   h1      bf16    196608
//   60555264   smallC  fp32     32768
//   60588032   bar     int       8192   (epoch at [2040])
//   60596224   G       fp32 402653184 | bf16 201326592   (layout [t][128][3072])

#define NB 128
#define LSEQ 256
#define LH 768
#define BGR 32768
#define NWG 96     // legacy path
#define PWG 192    // persistent path: 96 col-groups x 2 row-groups

typedef __attribute__((ext_vector_type(8))) short short8;
typedef __attribute__((ext_vector_type(4))) float floatx4;
typedef __attribute__((ext_vector_type(4))) unsigned int uint4v;

union frag16 { uint4v u; short8 s; };
union bfbits { __hip_bfloat16 h; unsigned short s; };

__device__ __forceinline__ float bf16bits_to_f(unsigned short s) {
    unsigned u = ((unsigned)s) << 16;
    float f;
    __builtin_memcpy(&f, &u, 4);
    return f;
}

// 8 MALL-coherent 16B loads at base + {0..448}
__device__ __forceinline__ void issue8(uint4v* b, const char* base) {
    asm volatile("global_load_dwordx4 %0, %1, off sc0 sc1"            : "=v"(b[0]) : "v"(base));
    asm volatile("global_load_dwordx4 %0, %1, off offset:64 sc0 sc1"  : "=v"(b[1]) : "v"(base));
    asm volatile("global_load_dwordx4 %0, %1, off offset:128 sc0 sc1" : "=v"(b[2]) : "v"(base));
    asm volatile("global_load_dwordx4 %0, %1, off offset:192 sc0 sc1" : "=v"(b[3]) : "v"(base));
    asm volatile("global_load_dwordx4 %0, %1, off offset:256 sc0 sc1" : "=v"(b[4]) : "v"(base));
    asm volatile("global_load_dwordx4 %0, %1, off offset:320 sc0 sc1" : "=v"(b[5]) : "v"(base));
    asm volatile("global_load_dwordx4 %0, %1, off offset:384 sc0 sc1" : "=v"(b[6]) : "v"(base));
    asm volatile("global_load_dwordx4 %0, %1, off offset:448 sc0 sc1" : "=v"(b[7]) : "v"(base));
}
// waitcnt with register ties so the compiler cannot hoist consumers above it
__device__ __forceinline__ void wait8_touch(uint4v* b) {
    asm volatile("s_waitcnt vmcnt(8)"
        : "+v"(b[0]), "+v"(b[1]), "+v"(b[2]), "+v"(b[3]),
          "+v"(b[4]), "+v"(b[5]), "+v"(b[6]), "+v"(b[7]) :: "memory");
}
__device__ __forceinline__ void wait0_touch(uint4v* b) {
    asm volatile("s_waitcnt vmcnt(0)"
        : "+v"(b[0]), "+v"(b[1]), "+v"(b[2]), "+v"(b[3]),
          "+v"(b[4]), "+v"(b[5]), "+v"(b[6]), "+v"(b[7]) :: "memory");
}

// ---------------- Canonicalize weights (fp32 inputs) ----------------
// smallC: W_pre@0(96) b_pre@96(32) W_gat@128(1024) att_src@1152(32)
//         att_dst@1184(32) b_gat@1216(32) b_ih@1248(3072) b_hh@4320(3072)
__global__ __launch_bounds__(256) void convert_kernel(
    const float* W_pre, const float* b_pre, const float* W_gat,
    const float* att_src, const float* att_dst, const float* b_gat,
    const float* W_ih, const float* W_hh, const float* b_ih, const float* b_hh,
    __hip_bfloat16* __restrict__ WihC, __hip_bfloat16* __restrict__ WhhC,
    float* __restrict__ smallC)
{
    long i = (long)blockIdx.x * 256 + threadIdx.x;
    if (i < 2359296) { WihC[i] = __float2bfloat16(W_ih[i]); return; }
    i -= 2359296;
    if (i < 2359296) { WhhC[i] = __float2bfloat16(W_hh[i]); return; }
    i -= 2359296;
    if (i < 96)   { smallC[0 + i]    = W_pre[i];   return; }  i -= 96;
    if (i < 32)   { smallC[96 + i]   = b_pre[i];   return; }  i -= 32;
    if (i < 1024) { smallC[128 + i]  = W_gat[i];   return; }  i -= 1024;
    if (i < 32)   { smallC[1152 + i] = att_src[i]; return; }  i -= 32;
    if (i < 32)   { smallC[1184 + i] = att_dst[i]; return; }  i -= 32;
    if (i < 32)   { smallC[1216 + i] = b_gat[i];   return; }  i -= 32;
    if (i < 3072) { smallC[1248 + i] = b_ih[i];    return; }  i -= 3072;
    if (i < 3072) { smallC[4320 + i] = b_hh[i];    return; }
}

// ---------------- Kernel A: pre + GAT -> Xb (bf16) ----------------
__global__ __launch_bounds__(256) void gat_pre_kernel(
    const float* __restrict__ src,           // [32768][72]
    const float* __restrict__ smallC,
    __hip_bfloat16* __restrict__ Xb)         // [32768][768]
{
    __shared__ float wpre[96];
    __shared__ float bpre[32];
    __shared__ float wgat[1024];
    __shared__ float asrc[32];
    __shared__ float adst[32];
    __shared__ float bgat[32];
    __shared__ float xl[8][72];
    __shared__ float hl[8][24][32];
    __shared__ float xpl[8][24][32];
    __shared__ float asl[8][24];
    __shared__ float adl[8][24];

    const int tid = threadIdx.x;
    for (int i = tid; i < 96; i += 256)   wpre[i] = smallC[i];
    for (int i = tid; i < 1024; i += 256) wgat[i] = smallC[128 + i];
    if (tid < 32) {
        bpre[tid] = smallC[96 + tid];
        asrc[tid] = smallC[1152 + tid];
        adst[tid] = smallC[1184 + tid];
        bgat[tid] = smallC[1216 + tid];
    }

    const int g = tid >> 5;
    const int k = tid & 31;
    const long gb = (long)blockIdx.x * 8 + g;   // graph id = n*256 + t

    for (int i = k; i < 72; i += 32)
        xl[g][i] = src[gb * 72 + i];
    __syncthreads();

    #pragma unroll
    for (int j = 0; j < 24; ++j) {
        float v = xl[g][j*3+0] * wpre[0*32+k]
                + xl[g][j*3+1] * wpre[1*32+k]
                + xl[g][j*3+2] * wpre[2*32+k] + bpre[k];
        hl[g][j][k] = tanhf(v);
    }
    __syncthreads();

    #pragma unroll
    for (int j = 0; j < 24; ++j) {
        float v = 0.f;
        #pragma unroll
        for (int m = 0; m < 32; ++m) v += hl[g][j][m] * wgat[m*32 + k];
        xpl[g][j][k] = v;
    }
    __syncthreads();

    if (k < 24) {
        float vs = 0.f, vd = 0.f;
        #pragma unroll
        for (int m = 0; m < 32; ++m) {
            float x = xpl[g][k][m];
            vs += x * asrc[m];
            vd += x * adst[m];
        }
        asl[g][k] = vs;
        adl[g][k] = vd;
    }
    __syncthreads();

    const int par[24] = {-1,0,0,0,1,2,3,4,5,6,7,8,9,9,9,12,13,14,16,17,18,19,20,21};
    #pragma unroll
    for (int j = 0; j < 24; ++j) {
        int p = par[j];
        float o;
        if (p < 0) {
            o = xpl[g][j][k] + bgat[k];
        } else {
            float es = adl[g][j] + asl[g][j];
            float ep = adl[g][j] + asl[g][p];
            es = es > 0.f ? es : 0.2f * es;
            ep = ep > 0.f ? ep : 0.2f * ep;
            float mx = fmaxf(es, ep);
            float wse = expf(es - mx), wpe = expf(ep - mx);
            float inv = 1.f / (wse + wpe);
            o = (wse * xpl[g][j][k] + wpe * xpl[g][p][k]) * inv + bgat[k];
        }
        Xb[gb * 768 + j * 32 + k] = __float2bfloat16(o);
    }
}

// ---------------- gates_in v2: G = X @ Wih^T + (b_ih+b_hh), 128x128 tiles ----------------
// grid (256, 24): bx = M-block (rows m*256+t of Xb), by = N-block (wrows).
// G layout [t][128][3072].
__global__ __launch_bounds__(256) void gates_in_kernel(
    const __hip_bfloat16* __restrict__ Xb,   // [32768][768]
    const __hip_bfloat16* __restrict__ Wih,  // [3072][768]
    const float* __restrict__ smallC,
    float* __restrict__ Gf, __hip_bfloat16* __restrict__ Gb, int ginf)
{
    const int tid = threadIdx.x;
    const int w = tid >> 6, L = tid & 63;
    const int rh2 = w >> 1, ch2 = w & 1;
    const int q = L >> 4, col16 = L & 15;
    const int R0 = blockIdx.x * 128;
    const int N0 = blockIdx.y * 128;

    const short8* ap[4];
    const short8* bp[4];
    #pragma unroll
    for (int i = 0; i < 4; ++i) {
        ap[i] = (const short8*)(Xb + (size_t)(R0 + 64*rh2 + 16*i + col16) * 768 + q*8);
        bp[i] = (const short8*)(Wih + (size_t)(N0 + 64*ch2 + 16*i + col16) * 768 + q*8);
    }

    floatx4 acc[4][4] = {};
    for (int kk = 0; kk < 24; ++kk) {
        short8 a[4], b[4];
        #pragma unroll
        for (int i = 0; i < 4; ++i) { a[i] = ap[i][kk*4]; b[i] = bp[i][kk*4]; }
        #pragma unroll
        for (int rt = 0; rt < 4; ++rt)
            #pragma unroll
            for (int bt = 0; bt < 4; ++bt)
                acc[rt][bt] = __builtin_amdgcn_mfma_f32_16x16x32_bf16(a[rt], b[bt], acc[rt][bt], 0, 0, 0);
    }

    #pragma unroll
    for (int bt = 0; bt < 4; ++bt) {
        int wrow = N0 + 64*ch2 + 16*bt + col16;
        float bias = smallC[1248 + wrow] + smallC[4320 + wrow];
        #pragma unroll
        for (int rt = 0; rt < 4; ++rt) {
            #pragma unroll
            for (int r = 0; r < 4; ++r) {
                int m_abs = R0 + 64*rh2 + 16*rt + q*4 + r;   // = m*256 + t
                int mm = m_abs >> 8, tt = m_abs & 255;
                size_t idx = ((size_t)tt * 128 + mm) * 3072 + wrow;
                float v = acc[rt][bt][r] + bias;
                if (ginf) Gf[idx] = v;
                else      Gb[idx] = __float2bfloat16(v);
            }
        }
    }
}

// ---------------- Persistent LSTM: all 256 steps in one launch ----------------
// 192 WGs: cg = bx%96 (units cg*8..+7, 32 gate cols), rg = bx/96 (rows rg*64..+63).
// Wave w = row quarter (16 rows). Whh slice in LDS (blocked, conflict-free).
// h via sc0/sc1 (MALL-coherent) -> no L2-flushing fences. Relaxed agent atomics barrier
// with arrival counters SPREAD across 128 B lines (the only change vs v1).
__global__ __launch_bounds__(256) void lstm_persist_kernel(
    const void* __restrict__ Gin,             // [t][128][3072] fp32 or bf16
    const __hip_bfloat16* __restrict__ Whh,   // [3072][768]
    __hip_bfloat16* __restrict__ h0g,         // ping-pong h (h0 zeroed)
    __hip_bfloat16* __restrict__ h1g,
    float* __restrict__ out,
    int* __restrict__ bar,                    // epoch at [2040]
    int* __restrict__ barU,                   // spread counters: [(t*10+g)*32], L2 at [(t*10+8)*32]
    int ginf)
{
    __shared__ short8 whhs[3072];             // [kk][c*4+q] 16B fragments, 48 KB
    __shared__ float gl[64 * 33];             // gate staging, 8448 B

    const int tid = threadIdx.x;
    const int w = tid >> 6;                   // row quarter: rows 16w..16w+15 (local)
    const int L = tid & 63;
    const int q = L >> 4;
    const int col16 = L & 15;
    const int cg = blockIdx.x % 96;
    const int rg = blockIdx.x / 96;

    // ---- stage Whh slice into LDS (once): whhs[f], f=(kk<<7)|(c<<2)|q ----
    for (int b = 0; b < 12; ++b) {
        int f = tid + 256 * b;
        int kk = f >> 7, c = (f >> 2) & 31, qq = f & 3;
        int wrow = 768 * (c >> 3) + cg * 8 + (c & 7);
        whhs[f] = *(const short8*)(Whh + (size_t)wrow * 768 + kk * 32 + qq * 8);
    }
    __syncthreads();

    // epilogue assignment: thread -> (row m_loc, unit pair u2b)
    const int m_loc = tid >> 2;               // 0..63
    const int u2b = (tid & 3) * 2;            // 0,2,4,6
    const int m_glob = rg * 64 + m_loc;
    float creg0 = 0.f, creg1 = 0.f;

    const float* Gf = (const float*)Gin;
    const __hip_bfloat16* Gb = (const __hip_bfloat16*)Gin;

    for (int t = 0; t < LSEQ; ++t) {
        const char* hr = (const char*)((t & 1) ? h1g : h0g);
        __hip_bfloat16* hw = (t & 1) ? h0g : h1g;

        // ---- G loads early (independent of h) ----
        const size_t grow = ((size_t)t * 128 + m_glob) * 3072 + cg * 8 + u2b;
        float gI0, gI1, gF0, gF1, gG0, gG1, gO0, gO1;
        if (ginf) {
            float2 vI = *(const float2*)(Gf + grow);
            float2 vF = *(const float2*)(Gf + grow + 768);
            float2 vG = *(const float2*)(Gf + grow + 1536);
            float2 vO = *(const float2*)(Gf + grow + 2304);
            gI0 = vI.x; gI1 = vI.y; gF0 = vF.x; gF1 = vF.y;
            gG0 = vG.x; gG1 = vG.y; gO0 = vO.x; gO1 = vO.y;
        } else {
            unsigned vi = *(const unsigned*)(Gb + grow);
            unsigned vf = *(const unsigned*)(Gb + grow + 768);
            unsigned vg = *(const unsigned*)(Gb + grow + 1536);
            unsigned vo = *(const unsigned*)(Gb + grow + 2304);
            gI0 = bf16bits_to_f(vi & 0xFFFF); gI1 = bf16bits_to_f(vi >> 16);
            gF0 = bf16bits_to_f(vf & 0xFFFF); gF1 = bf16bits_to_f(vf >> 16);
            gG0 = bf16bits_to_f(vg & 0xFFFF); gG1 = bf16bits_to_f(vg >> 16);
            gO0 = bf16bits_to_f(vo & 0xFFFF); gO1 = bf16bits_to_f(vo >> 16);
        }

        // ---- recurrent GEMM: A = h rows (16 per wave) from MALL, B = Whh from LDS ----
        floatx4 acc0 = {}, acc1 = {};
        uint4v bufA[8], bufB[8];
        const char* hbase = hr + (size_t)(((rg * 64 + 16 * w + col16) * 768) + q * 8) * 2;

        issue8(bufA, hbase);
        issue8(bufB, hbase + 512);

        wait8_touch(bufA);
        #pragma unroll
        for (int j = 0; j < 8; ++j) {
            frag16 fu; fu.u = bufA[j];
            short8 bv0 = whhs[j * 128 + (col16 * 4 + q)];
            short8 bv1 = whhs[j * 128 + ((16 + col16) * 4 + q)];
            acc0 = __builtin_amdgcn_mfma_f32_16x16x32_bf16(fu.s, bv0, acc0, 0, 0, 0);
            acc1 = __builtin_amdgcn_mfma_f32_16x16x32_bf16(fu.s, bv1, acc1, 0, 0, 0);
        }
        issue8(bufA, hbase + 1024);
        wait8_touch(bufB);
        #pragma unroll
        for (int j = 0; j < 8; ++j) {
            frag16 fu; fu.u = bufB[j];
            short8 bv0 = whhs[(8 + j) * 128 + (col16 * 4 + q)];
            short8 bv1 = whhs[(8 + j) * 128 + ((16 + col16) * 4 + q)];
            acc0 = __builtin_amdgcn_mfma_f32_16x16x32_bf16(fu.s, bv0, acc0, 0, 0, 0);
            acc1 = __builtin_amdgcn_mfma_f32_16x16x32_bf16(fu.s, bv1, acc1, 0, 0, 0);
        }
        wait0_touch(bufA);
        #pragma unroll
        for (int j = 0; j < 8; ++j) {
            frag16 fu; fu.u = bufA[j];
            short8 bv0 = whhs[(16 + j) * 128 + (col16 * 4 + q)];
            short8 bv1 = whhs[(16 + j) * 128 + ((16 + col16) * 4 + q)];
            acc0 = __builtin_amdgcn_mfma_f32_16x16x32_bf16(fu.s, bv0, acc0, 0, 0, 0);
            acc1 = __builtin_amdgcn_mfma_f32_16x16x32_bf16(fu.s, bv1, acc1, 0, 0, 0);
        }

        // ---- D -> gl: row = 16w + q*4 + r, cols col16 / 16+col16 ----
        #pragma unroll
        for (int r = 0; r < 4; ++r) {
            int mr = 16 * w + q * 4 + r;
            gl[mr * 33 + col16] = acc0[r];
            gl[mr * 33 + 16 + col16] = acc1[r];
        }
        __syncthreads();

        // ---- elementwise LSTM update (pair of units per thread) ----
        float ig0 = gI0 + gl[m_loc * 33 + 0  + u2b];
        float fg0 = gF0 + gl[m_loc * 33 + 8  + u2b];
        float gg0 = gG0 + gl[m_loc * 33 + 16 + u2b];
        float og0 = gO0 + gl[m_loc * 33 + 24 + u2b];
        float ig1 = gI1 + gl[m_loc * 33 + 0  + u2b + 1];
        float fg1 = gF1 + gl[m_loc * 33 + 8  + u2b + 1];
        float gg1 = gG1 + gl[m_loc * 33 + 16 + u2b + 1];
        float og1 = gO1 + gl[m_loc * 33 + 24 + u2b + 1];

        float si0 = 1.f / (1.f + expf(-ig0)), sf0 = 1.f / (1.f + expf(-fg0));
        float so0 = 1.f / (1.f + expf(-og0));
        float cn0 = sf0 * creg0 + si0 * tanhf(gg0);
        float hv0 = so0 * tanhf(cn0);
        creg0 = cn0;
        float si1 = 1.f / (1.f + expf(-ig1)), sf1 = 1.f / (1.f + expf(-fg1));
        float so1 = 1.f / (1.f + expf(-og1));
        float cn1 = sf1 * creg1 + si1 * tanhf(gg1);
        float hv1 = so1 * tanhf(cn1);
        creg1 = cn1;

        // h write: 2 bf16 packed, MALL-coherent
        bfbits b0, b1;
        b0.h = __float2bfloat16(hv0);
        b1.h = __float2bfloat16(hv1);
        unsigned hpack = (unsigned)b0.s | ((unsigned)b1.s << 16);
        char* ha = (char*)hw + (size_t)(m_glob * 768 + cg * 8 + u2b) * 2;
        asm volatile("global_store_dword %0, %1, off sc0 sc1" :: "v"(ha), "v"(hpack) : "memory");

        // out write (fp32)
        float2 ov; ov.x = hv0; ov.y = hv1;
        *(float2*)(out + ((size_t)m_glob * 256 + t) * 768 + cg * 8 + u2b) = ov;

        if (t == LSEQ - 1) {
            const size_t base = (size_t)NB * LSEQ * LH;
            const size_t ci = (size_t)m_glob * 768 + cg * 8 + u2b;
            float2 hv; hv.x = hv0; hv.y = hv1;
            float2 cv; cv.x = cn0; cv.y = cn1;
            *(float2*)(out + base + ci) = hv;
            *(float2*)(out + base + (size_t)NB * LH + ci) = cv;
        }

        // ---- grid barrier (two-level, relaxed agent atomics, no cache fences) ----
        // v4 change: arrival counters on separate 128 B lines (barU), epoch unchanged.
        if (t < LSEQ - 1) {
            asm volatile("s_waitcnt vmcnt(0)" ::: "memory");   // h at MALL
            __syncthreads();
            if (tid == 0) {
                int g = blockIdx.x & 7;
                int prev = __hip_atomic_fetch_add(&barU[(t * 10 + g) * 32], 1,
                                                  __ATOMIC_RELAXED, __HIP_MEMORY_SCOPE_AGENT);
                bool rel = false;
                if (prev == 23) {                              // 24th of this group
                    int pr = __hip_atomic_fetch_add(&barU[(t * 10 + 8) * 32], 1,
                                                    __ATOMIC_RELAXED, __HIP_MEMORY_SCOPE_AGENT);
                    if (pr == 7) {                             // 8th group
                        __hip_atomic_store(&bar[2040], t + 1,
                                           __ATOMIC_RELAXED, __HIP_MEMORY_SCOPE_AGENT);
                        rel = true;
                    }
                }
                if (!rel) {
                    while (__hip_atomic_load(&bar[2040], __ATOMIC_RELAXED,
                                             __HIP_MEMORY_SCOPE_AGENT) < t + 1)
                        __builtin_amdgcn_s_sleep(8);
                }
            }
            __syncthreads();
        }
    }
}

// ---------------- Legacy round-3 per-step path (ws fallback, proven) ----------------
__global__ __launch_bounds__(256) void lstm_step_kernel(
    const __hip_bfloat16* __restrict__ Xb,
    const __hip_bfloat16* __restrict__ Wih,
    const __hip_bfloat16* __restrict__ Whh,
    const float* __restrict__ smallC,
    float* __restrict__ cst,
    const __hip_bfloat16* __restrict__ hr,
    __hip_bfloat16* __restrict__ hw,
    float* __restrict__ out,
    int t)
{
    __shared__ float gls[128 * 33];
    const int tid = threadIdx.x;
    const int w = tid >> 6;
    const int L = tid & 63;
    const int rh = w >> 1;
    const int ct = w & 1;
    const int q = L >> 4;
    const int col16 = L & 15;
    const int c_local = 16 * ct + col16;
    const int gate = c_local >> 3;
    const int uu = c_local & 7;
    const int u = 8 * blockIdx.x + uu;
    const int wrow = 768 * gate + u;

    const short8* bp_i = (const short8*)(Wih + (long)wrow * 768 + q * 8);
    const short8* bp_h = (const short8*)(Whh + (long)wrow * 768 + q * 8);
    const short8* ap_x[4];
    const short8* ap_h[4];
    #pragma unroll
    for (int rt = 0; rt < 4; ++rt) {
        int m = 64 * rh + 16 * rt + col16;
        ap_x[rt] = (const short8*)(Xb + ((long)m * LSEQ + t) * 768 + q * 8);
        ap_h[rt] = (const short8*)(hr + (long)m * 768 + q * 8);
    }
    floatx4 acc[4] = {};
    for (int kk = 0; kk < 768; kk += 32) {
        short8 bv = bp_i[kk >> 3];
        #pragma unroll
        for (int rt = 0; rt < 4; ++rt)
            acc[rt] = __builtin_amdgcn_mfma_f32_16x16x32_bf16(ap_x[rt][kk >> 3], bv, acc[rt], 0, 0, 0);
    }
    for (int kk = 0; kk < 768; kk += 32) {
        short8 bv = bp_h[kk >> 3];
        #pragma unroll
        for (int rt = 0; rt < 4; ++rt)
            acc[rt] = __builtin_amdgcn_mfma_f32_16x16x32_bf16(ap_h[rt][kk >> 3], bv, acc[rt], 0, 0, 0);
    }
    float bias = smallC[1248 + wrow] + smallC[4320 + wrow];
    #pragma unroll
    for (int rt = 0; rt < 4; ++rt)
        #pragma unroll
        for (int r = 0; r < 4; ++r) {
            int m = 64 * rh + 16 * rt + q * 4 + r;
            gls[m * 33 + c_local] = acc[rt][r] + bias;
        }
    __syncthreads();
    for (int item = tid; item < 1024; item += 256) {
        int m = item >> 3;
        int u2l = item & 7;
        float ig = gls[m * 33 + 0  + u2l];
        float fg = gls[m * 33 + 8  + u2l];
        float gg = gls[m * 33 + 16 + u2l];
        float og = gls[m * 33 + 24 + u2l];
        int u2 = 8 * blockIdx.x + u2l;
        int ci = m * 768 + u2;
        float co = cst[ci];
        float si = 1.f / (1.f + expf(-ig));
        float sf = 1.f / (1.f + expf(-fg));
        float so = 1.f / (1.f + expf(-og));
        float cn = sf * co + si * tanhf(gg);
        float h = so * tanhf(cn);
        cst[ci] = cn;
        hw[ci] = __float2bfloat16(h);
        out[((long)m * LSEQ + t) * 768 + u2] = h;
    }
}

__global__ __launch_bounds__(256) void finalize_kernel(
    const __hip_bfloat16* __restrict__ hfin,
    const float* __restrict__ cst,
    float* __restrict__ out)
{
    int i = blockIdx.x * 256 + threadIdx.x;
    const long base = (long)NB * LSEQ * LH;
    out[base + i] = __bfloat162float(hfin[i]);
    out[base + NB * LH + i] = cst[i];
}

extern "C" void kernel_launch(void* const* d_in, const int* in_sizes, int n_in,
                              void* d_out, int out_size, void* d_ws, size_t ws_size,
                              hipStream_t stream) {
    const float* src     = (const float*)d_in[0];
    const float* W_pre   = (const float*)d_in[1];
    const float* b_pre   = (const float*)d_in[2];
    const float* W_gat   = (const float*)d_in[3];
    const float* att_src = (const float*)d_in[4];
    const float* att_dst = (const float*)d_in[5];
    const float* b_gat   = (const float*)d_in[6];
    const float* W_ih    = (const float*)d_in[7];
    const float* W_hh    = (const float*)d_in[8];
    const float* b_ih    = (const float*)d_in[9];
    const float* b_hh    = (const float*)d_in[10];

    float* out = (float*)d_out;
    char* ws = (char*)d_ws;

    __hip_bfloat16* Xb     = (__hip_bfloat16*)(ws);
    __hip_bfloat16* WihC   = (__hip_bfloat16*)(ws + 50331648);
    __hip_bfloat16* WhhC   = (__hip_bfloat16*)(ws + 55050240);
    float*          cs     = (float*)         (ws + 59768832);
    __hip_bfloat16* h0     = (__hip_bfloat16*)(ws + 60162048);
    __hip_bfloat16* h1     = (__hip_bfloat16*)(ws + 60358656);
    float*          smallC = (float*)         (ws + 60555264);
    int*            bar    = (int*)           (ws + 60588032);
    void*           Gin    = (void*)          (ws + 60596224);

    const size_t base_need = 60596224;
    const size_t need_f32  = base_need + (size_t)BGR * 3072 * 4;   // ~463 MB
    const size_t need_b16  = base_need + (size_t)BGR * 3072 * 2;   // ~262 MB
    const int use_persist  = (ws_size >= need_b16);
    const int ginf         = (ws_size >= need_f32);

    hipMemsetAsync(h0, 0, NB * LH * sizeof(__hip_bfloat16), stream);

    const long conv_total = 2359296L * 2 + 7392;
    convert_kernel<<<(int)((conv_total + 255) / 256), 256, 0, stream>>>(
        W_pre, b_pre, W_gat, att_src, att_dst, b_gat,
        W_ih, W_hh, b_ih, b_hh, WihC, WhhC, smallC);

    gat_pre_kernel<<<BGR / 8, 256, 0, stream>>>(src, smallC, Xb);

    if (use_persist) {
        hipMemsetAsync(bar, 0, 8192, stream);
        hipMemsetAsync(cs, 0, 327680, stream);   // spread arrival counters (barU)
        dim3 ggrid(256, 24);
        gates_in_kernel<<<ggrid, 256, 0, stream>>>(Xb, WihC, smallC,
                                                   (float*)Gin, (__hip_bfloat16*)Gin, ginf);
        lstm_persist_kernel<<<PWG, 256, 0, stream>>>(Gin, WhhC, h0, h1, out,
                                                     bar, (int*)cs, ginf);
    } else {
        hipMemsetAsync(cs, 0, NB * LH * sizeof(float), stream);
        __hip_bfloat16* hp[2] = {h0, h1};
        for (int t = 0; t < LSEQ; ++t) {
            lstm_step_kernel<<<NWG, 256, 0, stream>>>(Xb, WihC, WhhC, smallC,
                                                      cs, hp[t & 1], hp[(t + 1) & 1],
                                                      out, t);
        }
        finalize_kernel<<<NB * LH / 256, 256, 0, stream>>>(h0, cs, out);
    }
}

// Round 4
// 2590.677 us; speedup vs baseline: 3.1519x; 1.0304x over previous
//
#include <hip/hip_runtime.h>
#include <hip/hip_bf16.h>

// GraphEncoder: pre-Linear(3->32)+tanh -> GATConv(32->32, skeleton) -> LSTM(768->768, L=256)
// Inputs/outputs fp32. Compute: bf16 MFMA operands, fp32 accum/state.
//
// R7 (v5): v4 base (proven 2670 us total / 1886 us LSTM: spread barrier counters) + two
// local changes to the persistent kernel only:
//   1. G[t+1] register prefetch issued inside step t (post-consume, pre-store) so the
//      cold-HBM G latency drains in the pre-barrier vmcnt(0) instead of serially at
//      the next loop top. Barrier structure itself unchanged.
//   2. fast sigmoid/tanh via v_exp_f32/v_rcp_f32 (absmax-validated in R4's passing run).
//
// ws layout (bytes):
//   0          Xb      bf16  50331648
//   50331648   WihC    bf16   4718592
//   55050240   WhhC    bf16   4718592
//   59768832   cs      fp32    393216   (legacy: c state | persist: spread barU)
//   60162048   h0      bf16    196608
//   60358656   h1      bf16    196608
//   60555264   smallC  fp32     32768
//   60588032   bar     int       8192   (epoch at [2040])
//   60596224   G       fp32 402653184 | bf16 201326592   (layout [t][128][3072])

#define NB 128
#define LSEQ 256
#define LH 768
#define BGR 32768
#define NWG 96     // legacy path
#define PWG 192    // persistent path: 96 col-groups x 2 row-groups

typedef __attribute__((ext_vector_type(8))) short short8;
typedef __attribute__((ext_vector_type(4))) float floatx4;
typedef __attribute__((ext_vector_type(4))) unsigned int uint4v;

union frag16 { uint4v u; short8 s; };
union bfbits { __hip_bfloat16 h; unsigned short s; };

__device__ __forceinline__ float bf16bits_to_f(unsigned short s) {
    unsigned u = ((unsigned)s) << 16;
    float f;
    __builtin_memcpy(&f, &u, 4);
    return f;
}

// fast sigmoid/tanh: v_exp_f32 (2^x) + v_rcp_f32, ~2e-7 abs err (harness-validated R4)
__device__ __forceinline__ float fsig(float x) {
    return __builtin_amdgcn_rcpf(1.f + __builtin_amdgcn_exp2f(-1.44269504f * x));
}
__device__ __forceinline__ float ftanhf(float x) {
    return 1.f - 2.f * __builtin_amdgcn_rcpf(1.f + __builtin_amdgcn_exp2f(2.88539008f * x));
}

// 8 MALL-coherent 16B loads at base + {0..448}
__device__ __forceinline__ void issue8(uint4v* b, const char* base) {
    asm volatile("global_load_dwordx4 %0, %1, off sc0 sc1"            : "=v"(b[0]) : "v"(base));
    asm volatile("global_load_dwordx4 %0, %1, off offset:64 sc0 sc1"  : "=v"(b[1]) : "v"(base));
    asm volatile("global_load_dwordx4 %0, %1, off offset:128 sc0 sc1" : "=v"(b[2]) : "v"(base));
    asm volatile("global_load_dwordx4 %0, %1, off offset:192 sc0 sc1" : "=v"(b[3]) : "v"(base));
    asm volatile("global_load_dwordx4 %0, %1, off offset:256 sc0 sc1" : "=v"(b[4]) : "v"(base));
    asm volatile("global_load_dwordx4 %0, %1, off offset:320 sc0 sc1" : "=v"(b[5]) : "v"(base));
    asm volatile("global_load_dwordx4 %0, %1, off offset:384 sc0 sc1" : "=v"(b[6]) : "v"(base));
    asm volatile("global_load_dwordx4 %0, %1, off offset:448 sc0 sc1" : "=v"(b[7]) : "v"(base));
}
// waitcnt with register ties so the compiler cannot hoist consumers above it
__device__ __forceinline__ void wait8_touch(uint4v* b) {
    asm volatile("s_waitcnt vmcnt(8)"
        : "+v"(b[0]), "+v"(b[1]), "+v"(b[2]), "+v"(b[3]),
          "+v"(b[4]), "+v"(b[5]), "+v"(b[6]), "+v"(b[7]) :: "memory");
}
__device__ __forceinline__ void wait0_touch(uint4v* b) {
    asm volatile("s_waitcnt vmcnt(0)"
        : "+v"(b[0]), "+v"(b[1]), "+v"(b[2]), "+v"(b[3]),
          "+v"(b[4]), "+v"(b[5]), "+v"(b[6]), "+v"(b[7]) :: "memory");
}

// ---------------- Canonicalize weights (fp32 inputs) ----------------
// smallC: W_pre@0(96) b_pre@96(32) W_gat@128(1024) att_src@1152(32)
//         att_dst@1184(32) b_gat@1216(32) b_ih@1248(3072) b_hh@4320(3072)
__global__ __launch_bounds__(256) void convert_kernel(
    const float* W_pre, const float* b_pre, const float* W_gat,
    const float* att_src, const float* att_dst, const float* b_gat,
    const float* W_ih, const float* W_hh, const float* b_ih, const float* b_hh,
    __hip_bfloat16* __restrict__ WihC, __hip_bfloat16* __restrict__ WhhC,
    float* __restrict__ smallC)
{
    long i = (long)blockIdx.x * 256 + threadIdx.x;
    if (i < 2359296) { WihC[i] = __float2bfloat16(W_ih[i]); return; }
    i -= 2359296;
    if (i < 2359296) { WhhC[i] = __float2bfloat16(W_hh[i]); return; }
    i -= 2359296;
    if (i < 96)   { smallC[0 + i]    = W_pre[i];   return; }  i -= 96;
    if (i < 32)   { smallC[96 + i]   = b_pre[i];   return; }  i -= 32;
    if (i < 1024) { smallC[128 + i]  = W_gat[i];   return; }  i -= 1024;
    if (i < 32)   { smallC[1152 + i] = att_src[i]; return; }  i -= 32;
    if (i < 32)   { smallC[1184 + i] = att_dst[i]; return; }  i -= 32;
    if (i < 32)   { smallC[1216 + i] = b_gat[i];   return; }  i -= 32;
    if (i < 3072) { smallC[1248 + i] = b_ih[i];    return; }  i -= 3072;
    if (i < 3072) { smallC[4320 + i] = b_hh[i];    return; }
}

// ---------------- Kernel A: pre + GAT -> Xb (bf16) ----------------
__global__ __launch_bounds__(256) void gat_pre_kernel(
    const float* __restrict__ src,           // [32768][72]
    const float* __restrict__ smallC,
    __hip_bfloat16* __restrict__ Xb)         // [32768][768]
{
    __shared__ float wpre[96];
    __shared__ float bpre[32];
    __shared__ float wgat[1024];
    __shared__ float asrc[32];
    __shared__ float adst[32];
    __shared__ float bgat[32];
    __shared__ float xl[8][72];
    __shared__ float hl[8][24][32];
    __shared__ float xpl[8][24][32];
    __shared__ float asl[8][24];
    __shared__ float adl[8][24];

    const int tid = threadIdx.x;
    for (int i = tid; i < 96; i += 256)   wpre[i] = smallC[i];
    for (int i = tid; i < 1024; i += 256) wgat[i] = smallC[128 + i];
    if (tid < 32) {
        bpre[tid] = smallC[96 + tid];
        asrc[tid] = smallC[1152 + tid];
        adst[tid] = smallC[1184 + tid];
        bgat[tid] = smallC[1216 + tid];
    }

    const int g = tid >> 5;
    const int k = tid & 31;
    const long gb = (long)blockIdx.x * 8 + g;   // graph id = n*256 + t

    for (int i = k; i < 72; i += 32)
        xl[g][i] = src[gb * 72 + i];
    __syncthreads();

    #pragma unroll
    for (int j = 0; j < 24; ++j) {
        float v = xl[g][j*3+0] * wpre[0*32+k]
                + xl[g][j*3+1] * wpre[1*32+k]
                + xl[g][j*3+2] * wpre[2*32+k] + bpre[k];
        hl[g][j][k] = tanhf(v);
    }
    __syncthreads();

    #pragma unroll
    for (int j = 0; j < 24; ++j) {
        float v = 0.f;
        #pragma unroll
        for (int m = 0; m < 32; ++m) v += hl[g][j][m] * wgat[m*32 + k];
        xpl[g][j][k] = v;
    }
    __syncthreads();

    if (k < 24) {
        float vs = 0.f, vd = 0.f;
        #pragma unroll
        for (int m = 0; m < 32; ++m) {
            float x = xpl[g][k][m];
            vs += x * asrc[m];
            vd += x * adst[m];
        }
        asl[g][k] = vs;
        adl[g][k] = vd;
    }
    __syncthreads();

    const int par[24] = {-1,0,0,0,1,2,3,4,5,6,7,8,9,9,9,12,13,14,16,17,18,19,20,21};
    #pragma unroll
    for (int j = 0; j < 24; ++j) {
        int p = par[j];
        float o;
        if (p < 0) {
            o = xpl[g][j][k] + bgat[k];
        } else {
            float es = adl[g][j] + asl[g][j];
            float ep = adl[g][j] + asl[g][p];
            es = es > 0.f ? es : 0.2f * es;
            ep = ep > 0.f ? ep : 0.2f * ep;
            float mx = fmaxf(es, ep);
            float wse = expf(es - mx), wpe = expf(ep - mx);
            float inv = 1.f / (wse + wpe);
            o = (wse * xpl[g][j][k] + wpe * xpl[g][p][k]) * inv + bgat[k];
        }
        Xb[gb * 768 + j * 32 + k] = __float2bfloat16(o);
    }
}

// ---------------- gates_in v2: G = X @ Wih^T + (b_ih+b_hh), 128x128 tiles ----------------
// grid (256, 24): bx = M-block (rows m*256+t of Xb), by = N-block (wrows).
// G layout [t][128][3072].
__global__ __launch_bounds__(256) void gates_in_kernel(
    const __hip_bfloat16* __restrict__ Xb,   // [32768][768]
    const __hip_bfloat16* __restrict__ Wih,  // [3072][768]
    const float* __restrict__ smallC,
    float* __restrict__ Gf, __hip_bfloat16* __restrict__ Gb, int ginf)
{
    const int tid = threadIdx.x;
    const int w = tid >> 6, L = tid & 63;
    const int rh2 = w >> 1, ch2 = w & 1;
    const int q = L >> 4, col16 = L & 15;
    const int R0 = blockIdx.x * 128;
    const int N0 = blockIdx.y * 128;

    const short8* ap[4];
    const short8* bp[4];
    #pragma unroll
    for (int i = 0; i < 4; ++i) {
        ap[i] = (const short8*)(Xb + (size_t)(R0 + 64*rh2 + 16*i + col16) * 768 + q*8);
        bp[i] = (const short8*)(Wih + (size_t)(N0 + 64*ch2 + 16*i + col16) * 768 + q*8);
    }

    floatx4 acc[4][4] = {};
    for (int kk = 0; kk < 24; ++kk) {
        short8 a[4], b[4];
        #pragma unroll
        for (int i = 0; i < 4; ++i) { a[i] = ap[i][kk*4]; b[i] = bp[i][kk*4]; }
        #pragma unroll
        for (int rt = 0; rt < 4; ++rt)
            #pragma unroll
            for (int bt = 0; bt < 4; ++bt)
                acc[rt][bt] = __builtin_amdgcn_mfma_f32_16x16x32_bf16(a[rt], b[bt], acc[rt][bt], 0, 0, 0);
    }

    #pragma unroll
    for (int bt = 0; bt < 4; ++bt) {
        int wrow = N0 + 64*ch2 + 16*bt + col16;
        float bias = smallC[1248 + wrow] + smallC[4320 + wrow];
        #pragma unroll
        for (int rt = 0; rt < 4; ++rt) {
            #pragma unroll
            for (int r = 0; r < 4; ++r) {
                int m_abs = R0 + 64*rh2 + 16*rt + q*4 + r;   // = m*256 + t
                int mm = m_abs >> 8, tt = m_abs & 255;
                size_t idx = ((size_t)tt * 128 + mm) * 3072 + wrow;
                float v = acc[rt][bt][r] + bias;
                if (ginf) Gf[idx] = v;
                else      Gb[idx] = __float2bfloat16(v);
            }
        }
    }
}

// ---------------- Persistent LSTM: all 256 steps in one launch ----------------
// 192 WGs: cg = bx%96 (units cg*8..+7, 32 gate cols), rg = bx/96 (rows rg*64..+63).
// Wave w = row quarter (16 rows). Whh slice in LDS (blocked, conflict-free).
// h via sc0/sc1 (MALL-coherent). Spread-line arrival counters (proven v4).
// v5: G[t+1] prefetched into registers inside step t; fast sigmoid/tanh.
__global__ __launch_bounds__(256) void lstm_persist_kernel(
    const void* __restrict__ Gin,             // [t][128][3072] fp32 or bf16
    const __hip_bfloat16* __restrict__ Whh,   // [3072][768]
    __hip_bfloat16* __restrict__ h0g,         // ping-pong h (h0 zeroed)
    __hip_bfloat16* __restrict__ h1g,
    float* __restrict__ out,
    int* __restrict__ bar,                    // epoch at [2040]
    int* __restrict__ barU,                   // spread counters: [(t*10+g)*32], L2 at [(t*10+8)*32]
    int ginf)
{
    __shared__ short8 whhs[3072];             // [kk][c*4+q] 16B fragments, 48 KB
    __shared__ float gl[64 * 33];             // gate staging, 8448 B

    const int tid = threadIdx.x;
    const int w = tid >> 6;                   // row quarter: rows 16w..16w+15 (local)
    const int L = tid & 63;
    const int q = L >> 4;
    const int col16 = L & 15;
    const int cg = blockIdx.x % 96;
    const int rg = blockIdx.x / 96;

    // ---- stage Whh slice into LDS (once): whhs[f], f=(kk<<7)|(c<<2)|q ----
    for (int b = 0; b < 12; ++b) {
        int f = tid + 256 * b;
        int kk = f >> 7, c = (f >> 2) & 31, qq = f & 3;
        int wrow = 768 * (c >> 3) + cg * 8 + (c & 7);
        whhs[f] = *(const short8*)(Whh + (size_t)wrow * 768 + kk * 32 + qq * 8);
    }
    __syncthreads();

    // epilogue assignment: thread -> (row m_loc, unit pair u2b)
    const int m_loc = tid >> 2;               // 0..63
    const int u2b = (tid & 3) * 2;            // 0,2,4,6
    const int m_glob = rg * 64 + m_loc;
    float creg0 = 0.f, creg1 = 0.f;

    const float* Gf = (const float*)Gin;
    const __hip_bfloat16* Gb = (const __hip_bfloat16*)Gin;
    const size_t gcol = cg * 8 + u2b;

    // ---- G[0] register prefetch (fp32 path) ----
    float2 pI = {}, pF = {}, pG = {}, pO = {};
    if (ginf) {
        const float* gp = Gf + (size_t)m_glob * 3072 + gcol;
        pI = *(const float2*)(gp);
        pF = *(const float2*)(gp + 768);
        pG = *(const float2*)(gp + 1536);
        pO = *(const float2*)(gp + 2304);
    }

    for (int t = 0; t < LSEQ; ++t) {
        const char* hr = (const char*)((t & 1) ? h1g : h0g);
        __hip_bfloat16* hw = (t & 1) ? h0g : h1g;

        // ---- G values for this step ----
        float gI0, gI1, gF0, gF1, gG0, gG1, gO0, gO1;
        if (ginf) {
            gI0 = pI.x; gI1 = pI.y; gF0 = pF.x; gF1 = pF.y;
            gG0 = pG.x; gG1 = pG.y; gO0 = pO.x; gO1 = pO.y;
        } else {
            const size_t grow = ((size_t)t * 128 + m_glob) * 3072 + gcol;
            unsigned vi = *(const unsigned*)(Gb + grow);
            unsigned vf = *(const unsigned*)(Gb + grow + 768);
            unsigned vg = *(const unsigned*)(Gb + grow + 1536);
            unsigned vo = *(const unsigned*)(Gb + grow + 2304);
            gI0 = bf16bits_to_f(vi & 0xFFFF); gI1 = bf16bits_to_f(vi >> 16);
            gF0 = bf16bits_to_f(vf & 0xFFFF); gF1 = bf16bits_to_f(vf >> 16);
            gG0 = bf16bits_to_f(vg & 0xFFFF); gG1 = bf16bits_to_f(vg >> 16);
            gO0 = bf16bits_to_f(vo & 0xFFFF); gO1 = bf16bits_to_f(vo >> 16);
        }

        // ---- recurrent GEMM: A = h rows (16 per wave) from MALL, B = Whh from LDS ----
        floatx4 acc0 = {}, acc1 = {};
        uint4v bufA[8], bufB[8];
        const char* hbase = hr + (size_t)(((rg * 64 + 16 * w + col16) * 768) + q * 8) * 2;

        issue8(bufA, hbase);
        issue8(bufB, hbase + 512);

        wait8_touch(bufA);
        #pragma unroll
        for (int j = 0; j < 8; ++j) {
            frag16 fu; fu.u = bufA[j];
            short8 bv0 = whhs[j * 128 + (col16 * 4 + q)];
            short8 bv1 = whhs[j * 128 + ((16 + col16) * 4 + q)];
            acc0 = __builtin_amdgcn_mfma_f32_16x16x32_bf16(fu.s, bv0, acc0, 0, 0, 0);
            acc1 = __builtin_amdgcn_mfma_f32_16x16x32_bf16(fu.s, bv1, acc1, 0, 0, 0);
        }
        issue8(bufA, hbase + 1024);
        wait8_touch(bufB);
        #pragma unroll
        for (int j = 0; j < 8; ++j) {
            frag16 fu; fu.u = bufB[j];
            short8 bv0 = whhs[(8 + j) * 128 + (col16 * 4 + q)];
            short8 bv1 = whhs[(8 + j) * 128 + ((16 + col16) * 4 + q)];
            acc0 = __builtin_amdgcn_mfma_f32_16x16x32_bf16(fu.s, bv0, acc0, 0, 0, 0);
            acc1 = __builtin_amdgcn_mfma_f32_16x16x32_bf16(fu.s, bv1, acc1, 0, 0, 0);
        }
        wait0_touch(bufA);
        #pragma unroll
        for (int j = 0; j < 8; ++j) {
            frag16 fu; fu.u = bufA[j];
            short8 bv0 = whhs[(16 + j) * 128 + (col16 * 4 + q)];
            short8 bv1 = whhs[(16 + j) * 128 + ((16 + col16) * 4 + q)];
            acc0 = __builtin_amdgcn_mfma_f32_16x16x32_bf16(fu.s, bv0, acc0, 0, 0, 0);
            acc1 = __builtin_amdgcn_mfma_f32_16x16x32_bf16(fu.s, bv1, acc1, 0, 0, 0);
        }

        // ---- D -> gl: row = 16w + q*4 + r, cols col16 / 16+col16 ----
        #pragma unroll
        for (int r = 0; r < 4; ++r) {
            int mr = 16 * w + q * 4 + r;
            gl[mr * 33 + col16] = acc0[r];
            gl[mr * 33 + 16 + col16] = acc1[r];
        }
        __syncthreads();

        // ---- elementwise LSTM update (pair of units per thread) ----
        float ig0 = gI0 + gl[m_loc * 33 + 0  + u2b];
        float fg0 = gF0 + gl[m_loc * 33 + 8  + u2b];
        float gg0 = gG0 + gl[m_loc * 33 + 16 + u2b];
        float og0 = gO0 + gl[m_loc * 33 + 24 + u2b];
        float ig1 = gI1 + gl[m_loc * 33 + 0  + u2b + 1];
        float fg1 = gF1 + gl[m_loc * 33 + 8  + u2b + 1];
        float gg1 = gG1 + gl[m_loc * 33 + 16 + u2b + 1];
        float og1 = gO1 + gl[m_loc * 33 + 24 + u2b + 1];

        // ---- G[t+1] register prefetch: overlaps elementwise + stores, drains in
        //      the pre-barrier vmcnt(0) instead of post-barrier (v5 change) ----
        if (ginf && t < LSEQ - 1) {
            const float* gp = Gf + ((size_t)(t + 1) * 128 + m_glob) * 3072 + gcol;
            pI = *(const float2*)(gp);
            pF = *(const float2*)(gp + 768);
            pG = *(const float2*)(gp + 1536);
            pO = *(const float2*)(gp + 2304);
        }

        float si0 = fsig(ig0), sf0 = fsig(fg0), so0 = fsig(og0);
        float cn0 = sf0 * creg0 + si0 * ftanhf(gg0);
        float hv0 = so0 * ftanhf(cn0);
        creg0 = cn0;
        float si1 = fsig(ig1), sf1 = fsig(fg1), so1 = fsig(og1);
        float cn1 = sf1 * creg1 + si1 * ftanhf(gg1);
        float hv1 = so1 * ftanhf(cn1);
        creg1 = cn1;

        // h write: 2 bf16 packed, MALL-coherent
        bfbits b0, b1;
        b0.h = __float2bfloat16(hv0);
        b1.h = __float2bfloat16(hv1);
        unsigned hpack = (unsigned)b0.s | ((unsigned)b1.s << 16);
        char* ha = (char*)hw + (size_t)(m_glob * 768 + cg * 8 + u2b) * 2;
        asm volatile("global_store_dword %0, %1, off sc0 sc1" :: "v"(ha), "v"(hpack) : "memory");

        // out write (fp32)
        float2 ov; ov.x = hv0; ov.y = hv1;
        *(float2*)(out + ((size_t)m_glob * 256 + t) * 768 + cg * 8 + u2b) = ov;

        if (t == LSEQ - 1) {
            const size_t base = (size_t)NB * LSEQ * LH;
            const size_t ci = (size_t)m_glob * 768 + cg * 8 + u2b;
            float2 hv; hv.x = hv0; hv.y = hv1;
            float2 cv; cv.x = cn0; cv.y = cn1;
            *(float2*)(out + base + ci) = hv;
            *(float2*)(out + base + (size_t)NB * LH + ci) = cv;
        }

        // ---- grid barrier (two-level, relaxed agent atomics, spread lines) ----
        if (t < LSEQ - 1) {
            asm volatile("s_waitcnt vmcnt(0)" ::: "memory");   // h at MALL (+ G prefetch landed)
            __syncthreads();
            if (tid == 0) {
                int g = blockIdx.x & 7;
                int prev = __hip_atomic_fetch_add(&barU[(t * 10 + g) * 32], 1,
                                                  __ATOMIC_RELAXED, __HIP_MEMORY_SCOPE_AGENT);
                bool rel = false;
                if (prev == 23) {                              // 24th of this group
                    int pr = __hip_atomic_fetch_add(&barU[(t * 10 + 8) * 32], 1,
                                                    __ATOMIC_RELAXED, __HIP_MEMORY_SCOPE_AGENT);
                    if (pr == 7) {                             // 8th group
                        __hip_atomic_store(&bar[2040], t + 1,
                                           __ATOMIC_RELAXED, __HIP_MEMORY_SCOPE_AGENT);
                        rel = true;
                    }
                }
                if (!rel) {
                    while (__hip_atomic_load(&bar[2040], __ATOMIC_RELAXED,
                                             __HIP_MEMORY_SCOPE_AGENT) < t + 1)
                        __builtin_amdgcn_s_sleep(8);
                }
            }
            __syncthreads();
        }
    }
}

// ---------------- Legacy round-3 per-step path (ws fallback, proven) ----------------
__global__ __launch_bounds__(256) void lstm_step_kernel(
    const __hip_bfloat16* __restrict__ Xb,
    const __hip_bfloat16* __restrict__ Wih,
    const __hip_bfloat16* __restrict__ Whh,
    const float* __restrict__ smallC,
    float* __restrict__ cst,
    const __hip_bfloat16* __restrict__ hr,
    __hip_bfloat16* __restrict__ hw,
    float* __restrict__ out,
    int t)
{
    __shared__ float gls[128 * 33];
    const int tid = threadIdx.x;
    const int w = tid >> 6;
    const int L = tid & 63;
    const int rh = w >> 1;
    const int ct = w & 1;
    const int q = L >> 4;
    const int col16 = L & 15;
    const int c_local = 16 * ct + col16;
    const int gate = c_local >> 3;
    const int uu = c_local & 7;
    const int u = 8 * blockIdx.x + uu;
    const int wrow = 768 * gate + u;

    const short8* bp_i = (const short8*)(Wih + (long)wrow * 768 + q * 8);
    const short8* bp_h = (const short8*)(Whh + (long)wrow * 768 + q * 8);
    const short8* ap_x[4];
    const short8* ap_h[4];
    #pragma unroll
    for (int rt = 0; rt < 4; ++rt) {
        int m = 64 * rh + 16 * rt + col16;
        ap_x[rt] = (const short8*)(Xb + ((long)m * LSEQ + t) * 768 + q * 8);
        ap_h[rt] = (const short8*)(hr + (long)m * 768 + q * 8);
    }
    floatx4 acc[4] = {};
    for (int kk = 0; kk < 768; kk += 32) {
        short8 bv = bp_i[kk >> 3];
        #pragma unroll
        for (int rt = 0; rt < 4; ++rt)
            acc[rt] = __builtin_amdgcn_mfma_f32_16x16x32_bf16(ap_x[rt][kk >> 3], bv, acc[rt], 0, 0, 0);
    }
    for (int kk = 0; kk < 768; kk += 32) {
        short8 bv = bp_h[kk >> 3];
        #pragma unroll
        for (int rt = 0; rt < 4; ++rt)
            acc[rt] = __builtin_amdgcn_mfma_f32_16x16x32_bf16(ap_h[rt][kk >> 3], bv, acc[rt], 0, 0, 0);
    }
    float bias = smallC[1248 + wrow] + smallC[4320 + wrow];
    #pragma unroll
    for (int rt = 0; rt < 4; ++rt)
        #pragma unroll
        for (int r = 0; r < 4; ++r) {
            int m = 64 * rh + 16 * rt + q * 4 + r;
            gls[m * 33 + c_local] = acc[rt][r] + bias;
        }
    __syncthreads();
    for (int item = tid; item < 1024; item += 256) {
        int m = item >> 3;
        int u2l = item & 7;
        float ig = gls[m * 33 + 0  + u2l];
        float fg = gls[m * 33 + 8  + u2l];
        float gg = gls[m * 33 + 16 + u2l];
        float og = gls[m * 33 + 24 + u2l];
        int u2 = 8 * blockIdx.x + u2l;
        int ci = m * 768 + u2;
        float co = cst[ci];
        float si = 1.f / (1.f + expf(-ig));
        float sf = 1.f / (1.f + expf(-fg));
        float so = 1.f / (1.f + expf(-og));
        float cn = sf * co + si * tanhf(gg);
        float h = so * tanhf(cn);
        cst[ci] = cn;
        hw[ci] = __float2bfloat16(h);
        out[((long)m * LSEQ + t) * 768 + u2] = h;
    }
}

__global__ __launch_bounds__(256) void finalize_kernel(
    const __hip_bfloat16* __restrict__ hfin,
    const float* __restrict__ cst,
    float* __restrict__ out)
{
    int i = blockIdx.x * 256 + threadIdx.x;
    const long base = (long)NB * LSEQ * LH;
    out[base + i] = __bfloat162float(hfin[i]);
    out[base + NB * LH + i] = cst[i];
}

extern "C" void kernel_launch(void* const* d_in, const int* in_sizes, int n_in,
                              void* d_out, int out_size, void* d_ws, size_t ws_size,
                              hipStream_t stream) {
    const float* src     = (const float*)d_in[0];
    const float* W_pre   = (const float*)d_in[1];
    const float* b_pre   = (const float*)d_in[2];
    const float* W_gat   = (const float*)d_in[3];
    const float* att_src = (const float*)d_in[4];
    const float* att_dst = (const float*)d_in[5];
    const float* b_gat   = (const float*)d_in[6];
    const float* W_ih    = (const float*)d_in[7];
    const float* W_hh    = (const float*)d_in[8];
    const float* b_ih    = (const float*)d_in[9];
    const float* b_hh    = (const float*)d_in[10];

    float* out = (float*)d_out;
    char* ws = (char*)d_ws;

    __hip_bfloat16* Xb     = (__hip_bfloat16*)(ws);
    __hip_bfloat16* WihC   = (__hip_bfloat16*)(ws + 50331648);
    __hip_bfloat16* WhhC   = (__hip_bfloat16*)(ws + 55050240);
    float*          cs     = (float*)         (ws + 59768832);
    __hip_bfloat16* h0     = (__hip_bfloat16*)(ws + 60162048);
    __hip_bfloat16* h1     = (__hip_bfloat16*)(ws + 60358656);
    float*          smallC = (float*)         (ws + 60555264);
    int*            bar    = (int*)           (ws + 60588032);
    void*           Gin    = (void*)          (ws + 60596224);

    const size_t base_need = 60596224;
    const size_t need_f32  = base_need + (size_t)BGR * 3072 * 4;   // ~463 MB
    const size_t need_b16  = base_need + (size_t)BGR * 3072 * 2;   // ~262 MB
    const int use_persist  = (ws_size >= need_b16);
    const int ginf         = (ws_size >= need_f32);

    hipMemsetAsync(h0, 0, NB * LH * sizeof(__hip_bfloat16), stream);

    const long conv_total = 2359296L * 2 + 7392;
    convert_kernel<<<(int)((conv_total + 255) / 256), 256, 0, stream>>>(
        W_pre, b_pre, W_gat, att_src, att_dst, b_gat,
        W_ih, W_hh, b_ih, b_hh, WihC, WhhC, smallC);

    gat_pre_kernel<<<BGR / 8, 256, 0, stream>>>(src, smallC, Xb);

    if (use_persist) {
        hipMemsetAsync(bar, 0, 8192, stream);
        hipMemsetAsync(cs, 0, 327680, stream);   // spread arrival counters (barU)
        dim3 ggrid(256, 24);
        gates_in_kernel<<<ggrid, 256, 0, stream>>>(Xb, WihC, smallC,
                                                   (float*)Gin, (__hip_bfloat16*)Gin, ginf);
        lstm_persist_kernel<<<PWG, 256, 0, stream>>>(Gin, WhhC, h0, h1, out,
                                                     bar, (int*)cs, ginf);
    } else {
        hipMemsetAsync(cs, 0, NB * LH * sizeof(float), stream);
        __hip_bfloat16* hp[2] = {h0, h1};
        for (int t = 0; t < LSEQ; ++t) {
            lstm_step_kernel<<<NWG, 256, 0, stream>>>(Xb, WihC, WhhC, smallC,
                                                      cs, hp[t & 1], hp[(t + 1) & 1],
                                                      out, t);
        }
        finalize_kernel<<<NB * LH / 256, 256, 0, stream>>>(h0, cs, out);
    }
}

// Round 5
// 2508.746 us; speedup vs baseline: 3.2548x; 1.0327x over previous
//
#include <hip/hip_runtime.h>
#include <hip/hip_bf16.h>

// GraphEncoder: pre-Linear(3->32)+tanh -> GATConv(32->32, skeleton) -> LSTM(768->768, L=256)
// Inputs/outputs fp32. Compute: bf16 MFMA operands, fp32 accum/state.
//
// R8 (v6): v5 base (proven 2590 us total / 1801 us LSTM) + ONE structural change:
//   counted vmcnt(5) + raw s_barrier before the grid-barrier arrival, with issue
//   order [h store | out store | G[t+1] asm prefetch x4]. Retires ONLY the h store
//   before arrival; out-store HBM ack + G loads drain during the barrier wait.
//   G regs are consumed at the next step's vmcnt(8) wait (register-tied).
//   Plus s_sleep(8) -> s_sleep(2) poll quantum.
//
// ws layout (bytes):
//   0          Xb      bf16  50331648
//   50331648   WihC    bf16   4718592
//   55050240   WhhC    bf16   4718592
//   59768832   cs      fp32    393216   (legacy: c state | persist: spread barU)
//   60162048   h0      bf16    196608
//   60358656   h1      bf16    196608
//   60555264   smallC  fp32     32768
//   60588032   bar     int       8192   (epoch at [2040])
//   60596224   G       fp32 402653184 | bf16 201326592   (layout [t][128][3072])

#define NB 128
#define LSEQ 256
#define LH 768
#define BGR 32768
#define NWG 96     // legacy path
#define PWG 192    // persistent path: 96 col-groups x 2 row-groups

typedef __attribute__((ext_vector_type(8))) short short8;
typedef __attribute__((ext_vector_type(4))) float floatx4;
typedef __attribute__((ext_vector_type(4))) unsigned int uint4v;
typedef __attribute__((ext_vector_type(2))) unsigned int uint2v;

union frag16 { uint4v u; short8 s; };
union bfbits { __hip_bfloat16 h; unsigned short s; };
union uf2 { uint2v u; float f[2]; };

// fast sigmoid/tanh: v_exp_f32 (2^x) + v_rcp_f32 (harness-validated R4/R7)
__device__ __forceinline__ float fsig(float x) {
    return __builtin_amdgcn_rcpf(1.f + __builtin_amdgcn_exp2f(-1.44269504f * x));
}
__device__ __forceinline__ float ftanhf(float x) {
    return 1.f - 2.f * __builtin_amdgcn_rcpf(1.f + __builtin_amdgcn_exp2f(2.88539008f * x));
}

__device__ __forceinline__ float bf16bits_to_f(unsigned short s) {
    unsigned u = ((unsigned)s) << 16;
    float f;
    __builtin_memcpy(&f, &u, 4);
    return f;
}

// 8 MALL-coherent 16B loads at base + {0..448}
__device__ __forceinline__ void issue8(uint4v* b, const char* base) {
    asm volatile("global_load_dwordx4 %0, %1, off sc0 sc1"            : "=v"(b[0]) : "v"(base));
    asm volatile("global_load_dwordx4 %0, %1, off offset:64 sc0 sc1"  : "=v"(b[1]) : "v"(base));
    asm volatile("global_load_dwordx4 %0, %1, off offset:128 sc0 sc1" : "=v"(b[2]) : "v"(base));
    asm volatile("global_load_dwordx4 %0, %1, off offset:192 sc0 sc1" : "=v"(b[3]) : "v"(base));
    asm volatile("global_load_dwordx4 %0, %1, off offset:256 sc0 sc1" : "=v"(b[4]) : "v"(base));
    asm volatile("global_load_dwordx4 %0, %1, off offset:320 sc0 sc1" : "=v"(b[5]) : "v"(base));
    asm volatile("global_load_dwordx4 %0, %1, off offset:384 sc0 sc1" : "=v"(b[6]) : "v"(base));
    asm volatile("global_load_dwordx4 %0, %1, off offset:448 sc0 sc1" : "=v"(b[7]) : "v"(base));
}
// 4 asm 8B loads: gates I,F,G,O for 2 units (byte offsets 0,3072,6144,9216)
__device__ __forceinline__ void issueG2(uint2v* g, const char* gb) {
    const char* gb2 = gb + 6144;
    asm volatile("global_load_dwordx2 %0, %1, off"             : "=v"(g[0]) : "v"(gb));
    asm volatile("global_load_dwordx2 %0, %1, off offset:3072" : "=v"(g[1]) : "v"(gb));
    asm volatile("global_load_dwordx2 %0, %1, off"             : "=v"(g[2]) : "v"(gb2));
    asm volatile("global_load_dwordx2 %0, %1, off offset:3072" : "=v"(g[3]) : "v"(gb2));
}
// counted waits with register ties so consumers cannot be hoisted above them
__device__ __forceinline__ void wait8g_touch(uint4v* b, uint2v* g) {
    asm volatile("s_waitcnt vmcnt(8)"
        : "+v"(b[0]), "+v"(b[1]), "+v"(b[2]), "+v"(b[3]),
          "+v"(b[4]), "+v"(b[5]), "+v"(b[6]), "+v"(b[7]),
          "+v"(g[0]), "+v"(g[1]), "+v"(g[2]), "+v"(g[3]) :: "memory");
}
__device__ __forceinline__ void wait8_touch(uint4v* b) {
    asm volatile("s_waitcnt vmcnt(8)"
        : "+v"(b[0]), "+v"(b[1]), "+v"(b[2]), "+v"(b[3]),
          "+v"(b[4]), "+v"(b[5]), "+v"(b[6]), "+v"(b[7]) :: "memory");
}
__device__ __forceinline__ void wait0_touch(uint4v* b) {
    asm volatile("s_waitcnt vmcnt(0)"
        : "+v"(b[0]), "+v"(b[1]), "+v"(b[2]), "+v"(b[3]),
          "+v"(b[4]), "+v"(b[5]), "+v"(b[6]), "+v"(b[7]) :: "memory");
}

// ---------------- Canonicalize weights (fp32 inputs) ----------------
// smallC: W_pre@0(96) b_pre@96(32) W_gat@128(1024) att_src@1152(32)
//         att_dst@1184(32) b_gat@1216(32) b_ih@1248(3072) b_hh@4320(3072)
__global__ __launch_bounds__(256) void convert_kernel(
    const float* W_pre, const float* b_pre, const float* W_gat,
    const float* att_src, const float* att_dst, const float* b_gat,
    const float* W_ih, const float* W_hh, const float* b_ih, const float* b_hh,
    __hip_bfloat16* __restrict__ WihC, __hip_bfloat16* __restrict__ WhhC,
    float* __restrict__ smallC)
{
    long i = (long)blockIdx.x * 256 + threadIdx.x;
    if (i < 2359296) { WihC[i] = __float2bfloat16(W_ih[i]); return; }
    i -= 2359296;
    if (i < 2359296) { WhhC[i] = __float2bfloat16(W_hh[i]); return; }
    i -= 2359296;
    if (i < 96)   { smallC[0 + i]    = W_pre[i];   return; }  i -= 96;
    if (i < 32)   { smallC[96 + i]   = b_pre[i];   return; }  i -= 32;
    if (i < 1024) { smallC[128 + i]  = W_gat[i];   return; }  i -= 1024;
    if (i < 32)   { smallC[1152 + i] = att_src[i]; return; }  i -= 32;
    if (i < 32)   { smallC[1184 + i] = att_dst[i]; return; }  i -= 32;
    if (i < 32)   { smallC[1216 + i] = b_gat[i];   return; }  i -= 32;
    if (i < 3072) { smallC[1248 + i] = b_ih[i];    return; }  i -= 3072;
    if (i < 3072) { smallC[4320 + i] = b_hh[i];    return; }
}

// ---------------- Kernel A: pre + GAT -> Xb (bf16) ----------------
__global__ __launch_bounds__(256) void gat_pre_kernel(
    const float* __restrict__ src,           // [32768][72]
    const float* __restrict__ smallC,
    __hip_bfloat16* __restrict__ Xb)         // [32768][768]
{
    __shared__ float wpre[96];
    __shared__ float bpre[32];
    __shared__ float wgat[1024];
    __shared__ float asrc[32];
    __shared__ float adst[32];
    __shared__ float bgat[32];
    __shared__ float xl[8][72];
    __shared__ float hl[8][24][32];
    __shared__ float xpl[8][24][32];
    __shared__ float asl[8][24];
    __shared__ float adl[8][24];

    const int tid = threadIdx.x;
    for (int i = tid; i < 96; i += 256)   wpre[i] = smallC[i];
    for (int i = tid; i < 1024; i += 256) wgat[i] = smallC[128 + i];
    if (tid < 32) {
        bpre[tid] = smallC[96 + tid];
        asrc[tid] = smallC[1152 + tid];
        adst[tid] = smallC[1184 + tid];
        bgat[tid] = smallC[1216 + tid];
    }

    const int g = tid >> 5;
    const int k = tid & 31;
    const long gb = (long)blockIdx.x * 8 + g;   // graph id = n*256 + t

    for (int i = k; i < 72; i += 32)
        xl[g][i] = src[gb * 72 + i];
    __syncthreads();

    #pragma unroll
    for (int j = 0; j < 24; ++j) {
        float v = xl[g][j*3+0] * wpre[0*32+k]
                + xl[g][j*3+1] * wpre[1*32+k]
                + xl[g][j*3+2] * wpre[2*32+k] + bpre[k];
        hl[g][j][k] = tanhf(v);
    }
    __syncthreads();

    #pragma unroll
    for (int j = 0; j < 24; ++j) {
        float v = 0.f;
        #pragma unroll
        for (int m = 0; m < 32; ++m) v += hl[g][j][m] * wgat[m*32 + k];
        xpl[g][j][k] = v;
    }
    __syncthreads();

    if (k < 24) {
        float vs = 0.f, vd = 0.f;
        #pragma unroll
        for (int m = 0; m < 32; ++m) {
            float x = xpl[g][k][m];
            vs += x * asrc[m];
            vd += x * adst[m];
        }
        asl[g][k] = vs;
        adl[g][k] = vd;
    }
    __syncthreads();

    const int par[24] = {-1,0,0,0,1,2,3,4,5,6,7,8,9,9,9,12,13,14,16,17,18,19,20,21};
    #pragma unroll
    for (int j = 0; j < 24; ++j) {
        int p = par[j];
        float o;
        if (p < 0) {
            o = xpl[g][j][k] + bgat[k];
        } else {
            float es = adl[g][j] + asl[g][j];
            float ep = adl[g][j] + asl[g][p];
            es = es > 0.f ? es : 0.2f * es;
            ep = ep > 0.f ? ep : 0.2f * ep;
            float mx = fmaxf(es, ep);
            float wse = expf(es - mx), wpe = expf(ep - mx);
            float inv = 1.f / (wse + wpe);
            o = (wse * xpl[g][j][k] + wpe * xpl[g][p][k]) * inv + bgat[k];
        }
        Xb[gb * 768 + j * 32 + k] = __float2bfloat16(o);
    }
}

// ---------------- gates_in v2: G = X @ Wih^T + (b_ih+b_hh), 128x128 tiles ----------------
// grid (256, 24): bx = M-block (rows m*256+t of Xb), by = N-block (wrows).
// G layout [t][128][3072].
__global__ __launch_bounds__(256) void gates_in_kernel(
    const __hip_bfloat16* __restrict__ Xb,   // [32768][768]
    const __hip_bfloat16* __restrict__ Wih,  // [3072][768]
    const float* __restrict__ smallC,
    float* __restrict__ Gf, __hip_bfloat16* __restrict__ Gb, int ginf)
{
    const int tid = threadIdx.x;
    const int w = tid >> 6, L = tid & 63;
    const int rh2 = w >> 1, ch2 = w & 1;
    const int q = L >> 4, col16 = L & 15;
    const int R0 = blockIdx.x * 128;
    const int N0 = blockIdx.y * 128;

    const short8* ap[4];
    const short8* bp[4];
    #pragma unroll
    for (int i = 0; i < 4; ++i) {
        ap[i] = (const short8*)(Xb + (size_t)(R0 + 64*rh2 + 16*i + col16) * 768 + q*8);
        bp[i] = (const short8*)(Wih + (size_t)(N0 + 64*ch2 + 16*i + col16) * 768 + q*8);
    }

    floatx4 acc[4][4] = {};
    for (int kk = 0; kk < 24; ++kk) {
        short8 a[4], b[4];
        #pragma unroll
        for (int i = 0; i < 4; ++i) { a[i] = ap[i][kk*4]; b[i] = bp[i][kk*4]; }
        #pragma unroll
        for (int rt = 0; rt < 4; ++rt)
            #pragma unroll
            for (int bt = 0; bt < 4; ++bt)
                acc[rt][bt] = __builtin_amdgcn_mfma_f32_16x16x32_bf16(a[rt], b[bt], acc[rt][bt], 0, 0, 0);
    }

    #pragma unroll
    for (int bt = 0; bt < 4; ++bt) {
        int wrow = N0 + 64*ch2 + 16*bt + col16;
        float bias = smallC[1248 + wrow] + smallC[4320 + wrow];
        #pragma unroll
        for (int rt = 0; rt < 4; ++rt) {
            #pragma unroll
            for (int r = 0; r < 4; ++r) {
                int m_abs = R0 + 64*rh2 + 16*rt + q*4 + r;   // = m*256 + t
                int mm = m_abs >> 8, tt = m_abs & 255;
                size_t idx = ((size_t)tt * 128 + mm) * 3072 + wrow;
                float v = acc[rt][bt][r] + bias;
                if (ginf) Gf[idx] = v;
                else      Gb[idx] = __float2bfloat16(v);
            }
        }
    }
}

// ---------------- Persistent LSTM: all 256 steps in one launch ----------------
// 192 WGs: cg = bx%96 (units cg*8..+7, 32 gate cols), rg = bx/96 (rows rg*64..+63).
// Wave w = row quarter (16 rows). Whh slice in LDS (blocked, conflict-free).
// h via sc0/sc1 (MALL-coherent). Spread-line arrival counters (proven v4).
// v6: counted vmcnt(5) + raw s_barrier pre-arrival; G[t+1] asm-prefetched behind
// the h store, retired at the next step's vmcnt(8); s_sleep(2) poll.
__global__ __launch_bounds__(256) void lstm_persist_kernel(
    const void* __restrict__ Gin,             // [t][128][3072] fp32 or bf16
    const __hip_bfloat16* __restrict__ Whh,   // [3072][768]
    __hip_bfloat16* __restrict__ h0g,         // ping-pong h (h0 zeroed)
    __hip_bfloat16* __restrict__ h1g,
    float* __restrict__ out,
    int* __restrict__ bar,                    // epoch at [2040]
    int* __restrict__ barU,                   // spread counters: [(t*10+g)*32], L2 at [(t*10+8)*32]
    int ginf)
{
    __shared__ short8 whhs[3072];             // [kk][c*4+q] 16B fragments, 48 KB
    __shared__ float gl[64 * 33];             // gate staging, 8448 B

    const int tid = threadIdx.x;
    const int w = tid >> 6;                   // row quarter: rows 16w..16w+15 (local)
    const int L = tid & 63;
    const int q = L >> 4;
    const int col16 = L & 15;
    const int cg = blockIdx.x % 96;
    const int rg = blockIdx.x / 96;

    // ---- stage Whh slice into LDS (once): whhs[f], f=(kk<<7)|(c<<2)|q ----
    for (int b = 0; b < 12; ++b) {
        int f = tid + 256 * b;
        int kk = f >> 7, c = (f >> 2) & 31, qq = f & 3;
        int wrow = 768 * (c >> 3) + cg * 8 + (c & 7);
        whhs[f] = *(const short8*)(Whh + (size_t)wrow * 768 + kk * 32 + qq * 8);
    }
    __syncthreads();

    // epilogue assignment: thread -> (row m_loc, unit pair u2b)
    const int m_loc = tid >> 2;               // 0..63
    const int u2b = (tid & 3) * 2;            // 0,2,4,6
    const int m_glob = rg * 64 + m_loc;
    float creg0 = 0.f, creg1 = 0.f;

    const float* Gf = (const float*)Gin;
    const __hip_bfloat16* Gb = (const __hip_bfloat16*)Gin;
    const size_t gcol = cg * 8 + u2b;

    // ---- G[0] asm prefetch (fp32 path): queue [G x4] at loop entry ----
    uint2v gp[4] = {};
    if (ginf)
        issueG2(gp, (const char*)(Gf + (size_t)m_glob * 3072 + gcol));

    for (int t = 0; t < LSEQ; ++t) {
        const char* hr = (const char*)((t & 1) ? h1g : h0g);
        __hip_bfloat16* hw = (t & 1) ? h0g : h1g;

        // ---- recurrent GEMM: A = h rows (16 per wave) from MALL, B = Whh from LDS ----
        // steady-state queue at entry: [out x1, G x4] (older) — vmcnt(8) after the
        // 16 h-loads retires exactly [out, G x4, bufA x8]; G regs tied here.
        floatx4 acc0 = {}, acc1 = {};
        uint4v bufA[8], bufB[8];
        const char* hbase = hr + (size_t)(((rg * 64 + 16 * w + col16) * 768) + q * 8) * 2;

        issue8(bufA, hbase);
        issue8(bufB, hbase + 512);

        wait8g_touch(bufA, gp);
        #pragma unroll
        for (int j = 0; j < 8; ++j) {
            frag16 fu; fu.u = bufA[j];
            short8 bv0 = whhs[j * 128 + (col16 * 4 + q)];
            short8 bv1 = whhs[j * 128 + ((16 + col16) * 4 + q)];
            acc0 = __builtin_amdgcn_mfma_f32_16x16x32_bf16(fu.s, bv0, acc0, 0, 0, 0);
            acc1 = __builtin_amdgcn_mfma_f32_16x16x32_bf16(fu.s, bv1, acc1, 0, 0, 0);
        }
        issue8(bufA, hbase + 1024);
        wait8_touch(bufB);
        #pragma unroll
        for (int j = 0; j < 8; ++j) {
            frag16 fu; fu.u = bufB[j];
            short8 bv0 = whhs[(8 + j) * 128 + (col16 * 4 + q)];
            short8 bv1 = whhs[(8 + j) * 128 + ((16 + col16) * 4 + q)];
            acc0 = __builtin_amdgcn_mfma_f32_16x16x32_bf16(fu.s, bv0, acc0, 0, 0, 0);
            acc1 = __builtin_amdgcn_mfma_f32_16x16x32_bf16(fu.s, bv1, acc1, 0, 0, 0);
        }
        wait0_touch(bufA);
        #pragma unroll
        for (int j = 0; j < 8; ++j) {
            frag16 fu; fu.u = bufA[j];
            short8 bv0 = whhs[(16 + j) * 128 + (col16 * 4 + q)];
            short8 bv1 = whhs[(16 + j) * 128 + ((16 + col16) * 4 + q)];
            acc0 = __builtin_amdgcn_mfma_f32_16x16x32_bf16(fu.s, bv0, acc0, 0, 0, 0);
            acc1 = __builtin_amdgcn_mfma_f32_16x16x32_bf16(fu.s, bv1, acc1, 0, 0, 0);
        }

        // ---- D -> gl: row = 16w + q*4 + r, cols col16 / 16+col16 ----
        #pragma unroll
        for (int r = 0; r < 4; ++r) {
            int mr = 16 * w + q * 4 + r;
            gl[mr * 33 + col16] = acc0[r];
            gl[mr * 33 + 16 + col16] = acc1[r];
        }
        __syncthreads();

        // ---- G values for this step (fp32: from retired asm prefetch regs) ----
        float gI0, gI1, gF0, gF1, gG0, gG1, gO0, gO1;
        if (ginf) {
            uf2 uI, uF, uG, uO;
            uI.u = gp[0]; uF.u = gp[1]; uG.u = gp[2]; uO.u = gp[3];
            gI0 = uI.f[0]; gI1 = uI.f[1]; gF0 = uF.f[0]; gF1 = uF.f[1];
            gG0 = uG.f[0]; gG1 = uG.f[1]; gO0 = uO.f[0]; gO1 = uO.f[1];
        } else {
            const size_t grow = ((size_t)t * 128 + m_glob) * 3072 + gcol;
            unsigned vi = *(const unsigned*)(Gb + grow);
            unsigned vf = *(const unsigned*)(Gb + grow + 768);
            unsigned vg = *(const unsigned*)(Gb + grow + 1536);
            unsigned vo = *(const unsigned*)(Gb + grow + 2304);
            gI0 = bf16bits_to_f(vi & 0xFFFF); gI1 = bf16bits_to_f(vi >> 16);
            gF0 = bf16bits_to_f(vf & 0xFFFF); gF1 = bf16bits_to_f(vf >> 16);
            gG0 = bf16bits_to_f(vg & 0xFFFF); gG1 = bf16bits_to_f(vg >> 16);
            gO0 = bf16bits_to_f(vo & 0xFFFF); gO1 = bf16bits_to_f(vo >> 16);
        }

        // ---- elementwise LSTM update (pair of units per thread) ----
        float ig0 = gI0 + gl[m_loc * 33 + 0  + u2b];
        float fg0 = gF0 + gl[m_loc * 33 + 8  + u2b];
        float gg0 = gG0 + gl[m_loc * 33 + 16 + u2b];
        float og0 = gO0 + gl[m_loc * 33 + 24 + u2b];
        float ig1 = gI1 + gl[m_loc * 33 + 0  + u2b + 1];
        float fg1 = gF1 + gl[m_loc * 33 + 8  + u2b + 1];
        float gg1 = gG1 + gl[m_loc * 33 + 16 + u2b + 1];
        float og1 = gO1 + gl[m_loc * 33 + 24 + u2b + 1];

        float si0 = fsig(ig0), sf0 = fsig(fg0), so0 = fsig(og0);
        float cn0 = sf0 * creg0 + si0 * ftanhf(gg0);
        float hv0 = so0 * ftanhf(cn0);
        creg0 = cn0;
        float si1 = fsig(ig1), sf1 = fsig(fg1), so1 = fsig(og1);
        float cn1 = sf1 * creg1 + si1 * ftanhf(gg1);
        float hv1 = so1 * ftanhf(cn1);
        creg1 = cn1;

        bfbits b0, b1;
        b0.h = __float2bfloat16(hv0);
        b1.h = __float2bfloat16(hv1);
        unsigned hpack = (unsigned)b0.s | ((unsigned)b1.s << 16);
        char* ha = (char*)hw + (size_t)(m_glob * 768 + cg * 8 + u2b) * 2;
        float2 ov; ov.x = hv0; ov.y = hv1;
        float* oa = out + ((size_t)m_glob * 256 + t) * 768 + cg * 8 + u2b;

        if (t < LSEQ - 1) {
            // issue order: h store (oldest) | out store | G[t+1] x4
            // vmcnt(5) retires exactly the h store; out + G drain during barrier.
            asm volatile("global_store_dword %0, %1, off sc0 sc1" :: "v"(ha), "v"(hpack) : "memory");
            asm volatile("global_store_dwordx2 %0, %1, off" :: "v"(oa), "v"(ov) : "memory");
            if (ginf)
                issueG2(gp, (const char*)(Gf + ((size_t)(t + 1) * 128 + m_glob) * 3072 + gcol));
            asm volatile("s_waitcnt vmcnt(5)" ::: "memory");
            __builtin_amdgcn_s_barrier();     // all waves' h stores retired
            if (tid == 0) {
                int g = blockIdx.x & 7;
                int prev = __hip_atomic_fetch_add(&barU[(t * 10 + g) * 32], 1,
                                                  __ATOMIC_RELAXED, __HIP_MEMORY_SCOPE_AGENT);
                bool rel = false;
                if (prev == 23) {                              // 24th of this group
                    int pr = __hip_atomic_fetch_add(&barU[(t * 10 + 8) * 32], 1,
                                                    __ATOMIC_RELAXED, __HIP_MEMORY_SCOPE_AGENT);
                    if (pr == 7) {                             // 8th group
                        __hip_atomic_store(&bar[2040], t + 1,
                                           __ATOMIC_RELAXED, __HIP_MEMORY_SCOPE_AGENT);
                        rel = true;
                    }
                }
                if (!rel) {
                    while (__hip_atomic_load(&bar[2040], __ATOMIC_RELAXED,
                                             __HIP_MEMORY_SCOPE_AGENT) < t + 1)
                        __builtin_amdgcn_s_sleep(2);
                }
            }
            __builtin_amdgcn_s_barrier();
        } else {
            asm volatile("global_store_dwordx2 %0, %1, off" :: "v"(oa), "v"(ov) : "memory");
            const size_t base = (size_t)NB * LSEQ * LH;
            const size_t ci = (size_t)m_glob * 768 + cg * 8 + u2b;
            float2 hv; hv.x = hv0; hv.y = hv1;
            float2 cv; cv.x = cn0; cv.y = cn1;
            *(float2*)(out + base + ci) = hv;
            *(float2*)(out + base + (size_t)NB * LH + ci) = cv;
        }
    }
}

// ---------------- Legacy round-3 per-step path (ws fallback, proven) ----------------
__global__ __launch_bounds__(256) void lstm_step_kernel(
    const __hip_bfloat16* __restrict__ Xb,
    const __hip_bfloat16* __restrict__ Wih,
    const __hip_bfloat16* __restrict__ Whh,
    const float* __restrict__ smallC,
    float* __restrict__ cst,
    const __hip_bfloat16* __restrict__ hr,
    __hip_bfloat16* __restrict__ hw,
    float* __restrict__ out,
    int t)
{
    __shared__ float gls[128 * 33];
    const int tid = threadIdx.x;
    const int w = tid >> 6;
    const int L = tid & 63;
    const int rh = w >> 1;
    const int ct = w & 1;
    const int q = L >> 4;
    const int col16 = L & 15;
    const int c_local = 16 * ct + col16;
    const int gate = c_local >> 3;
    const int uu = c_local & 7;
    const int u = 8 * blockIdx.x + uu;
    const int wrow = 768 * gate + u;

    const short8* bp_i = (const short8*)(Wih + (long)wrow * 768 + q * 8);
    const short8* bp_h = (const short8*)(Whh + (long)wrow * 768 + q * 8);
    const short8* ap_x[4];
    const short8* ap_h[4];
    #pragma unroll
    for (int rt = 0; rt < 4; ++rt) {
        int m = 64 * rh + 16 * rt + col16;
        ap_x[rt] = (const short8*)(Xb + ((long)m * LSEQ + t) * 768 + q * 8);
        ap_h[rt] = (const short8*)(hr + (long)m * 768 + q * 8);
    }
    floatx4 acc[4] = {};
    for (int kk = 0; kk < 768; kk += 32) {
        short8 bv = bp_i[kk >> 3];
        #pragma unroll
        for (int rt = 0; rt < 4; ++rt)
            acc[rt] = __builtin_amdgcn_mfma_f32_16x16x32_bf16(ap_x[rt][kk >> 3], bv, acc[rt], 0, 0, 0);
    }
    for (int kk = 0; kk < 768; kk += 32) {
        short8 bv = bp_h[kk >> 3];
        #pragma unroll
        for (int rt = 0; rt < 4; ++rt)
            acc[rt] = __builtin_amdgcn_mfma_f32_16x16x32_bf16(ap_h[rt][kk >> 3], bv, acc[rt], 0, 0, 0);
    }
    float bias = smallC[1248 + wrow] + smallC[4320 + wrow];
    #pragma unroll
    for (int rt = 0; rt < 4; ++rt)
        #pragma unroll
        for (int r = 0; r < 4; ++r) {
            int m = 64 * rh + 16 * rt + q * 4 + r;
            gls[m * 33 + c_local] = acc[rt][r] + bias;
        }
    __syncthreads();
    for (int item = tid; item < 1024; item += 256) {
        int m = item >> 3;
        int u2l = item & 7;
        float ig = gls[m * 33 + 0  + u2l];
        float fg = gls[m * 33 + 8  + u2l];
        float gg = gls[m * 33 + 16 + u2l];
        float og = gls[m * 33 + 24 + u2l];
        int u2 = 8 * blockIdx.x + u2l;
        int ci = m * 768 + u2;
        float co = cst[ci];
        float si = 1.f / (1.f + expf(-ig));
        float sf = 1.f / (1.f + expf(-fg));
        float so = 1.f / (1.f + expf(-og));
        float cn = sf * co + si * tanhf(gg);
        float h = so * tanhf(cn);
        cst[ci] = cn;
        hw[ci] = __float2bfloat16(h);
        out[((long)m * LSEQ + t) * 768 + u2] = h;
    }
}

__global__ __launch_bounds__(256) void finalize_kernel(
    const __hip_bfloat16* __restrict__ hfin,
    const float* __restrict__ cst,
    float* __restrict__ out)
{
    int i = blockIdx.x * 256 + threadIdx.x;
    const long base = (long)NB * LSEQ * LH;
    out[base + i] = __bfloat162float(hfin[i]);
    out[base + NB * LH + i] = cst[i];
}

extern "C" void kernel_launch(void* const* d_in, const int* in_sizes, int n_in,
                              void* d_out, int out_size, void* d_ws, size_t ws_size,
                              hipStream_t stream) {
    const float* src     = (const float*)d_in[0];
    const float* W_pre   = (const float*)d_in[1];
    const float* b_pre   = (const float*)d_in[2];
    const float* W_gat   = (const float*)d_in[3];
    const float* att_src = (const float*)d_in[4];
    const float* att_dst = (const float*)d_in[5];
    const float* b_gat   = (const float*)d_in[6];
    const float* W_ih    = (const float*)d_in[7];
    const float* W_hh    = (const float*)d_in[8];
    const float* b_ih    = (const float*)d_in[9];
    const float* b_hh    = (const float*)d_in[10];

    float* out = (float*)d_out;
    char* ws = (char*)d_ws;

    __hip_bfloat16* Xb     = (__hip_bfloat16*)(ws);
    __hip_bfloat16* WihC   = (__hip_bfloat16*)(ws + 50331648);
    __hip_bfloat16* WhhC   = (__hip_bfloat16*)(ws + 55050240);
    float*          cs     = (float*)         (ws + 59768832);
    __hip_bfloat16* h0     = (__hip_bfloat16*)(ws + 60162048);
    __hip_bfloat16* h1     = (__hip_bfloat16*)(ws + 60358656);
    float*          smallC = (float*)         (ws + 60555264);
    int*            bar    = (int*)           (ws + 60588032);
    void*           Gin    = (void*)          (ws + 60596224);

    const size_t base_need = 60596224;
    const size_t need_f32  = base_need + (size_t)BGR * 3072 * 4;   // ~463 MB
    const size_t need_b16  = base_need + (size_t)BGR * 3072 * 2;   // ~262 MB
    const int use_persist  = (ws_size >= need_b16);
    const int ginf         = (ws_size >= need_f32);

    hipMemsetAsync(h0, 0, NB * LH * sizeof(__hip_bfloat16), stream);

    const long conv_total = 2359296L * 2 + 7392;
    convert_kernel<<<(int)((conv_total + 255) / 256), 256, 0, stream>>>(
        W_pre, b_pre, W_gat, att_src, att_dst, b_gat,
        W_ih, W_hh, b_ih, b_hh, WihC, WhhC, smallC);

    gat_pre_kernel<<<BGR / 8, 256, 0, stream>>>(src, smallC, Xb);

    if (use_persist) {
        hipMemsetAsync(bar, 0, 8192, stream);
        hipMemsetAsync(cs, 0, 327680, stream);   // spread arrival counters (barU)
        dim3 ggrid(256, 24);
        gates_in_kernel<<<ggrid, 256, 0, stream>>>(Xb, WihC, smallC,
                                                   (float*)Gin, (__hip_bfloat16*)Gin, ginf);
        lstm_persist_kernel<<<PWG, 256, 0, stream>>>(Gin, WhhC, h0, h1, out,
                                                     bar, (int*)cs, ginf);
    } else {
        hipMemsetAsync(cs, 0, NB * LH * sizeof(float), stream);
        __hip_bfloat16* hp[2] = {h0, h1};
        for (int t = 0; t < LSEQ; ++t) {
            lstm_step_kernel<<<NWG, 256, 0, stream>>>(Xb, WihC, WhhC, smallC,
                                                      cs, hp[t & 1], hp[(t + 1) & 1],
                                                      out, t);
        }
        finalize_kernel<<<NB * LH / 256, 256, 0, stream>>>(h0, cs, out);
    }
}

// Round 6
// 2450.752 us; speedup vs baseline: 3.3318x; 1.0237x over previous
//
#include <hip/hip_runtime.h>
#include <hip/hip_bf16.h>

// GraphEncoder: pre-Linear(3->32)+tanh -> GATConv(32->32, skeleton) -> LSTM(768->768, L=256)
// Inputs/outputs fp32. Compute: bf16 MFMA operands, fp32 accum/state.
//
// R9 (v7): v6 base (proven 2508 us total / 1712 us LSTM) + two changes:
//   1. Per-row-group barriers: rg=0 and rg=1 sync independently (96 WGs each,
//      8 groups x 12), accumulating counters (no t-indexing), per-rg epoch.
//      Correct because WG (cg,rg) only reads h rows written by same-rg WGs.
//   2. All 24 h loads issued up front (bufA/bufB/bufC); waits vmcnt(16)/8/0.
//
// ws layout (bytes):
//   0          Xb      bf16  50331648
//   50331648   WihC    bf16   4718592
//   55050240   WhhC    bf16   4718592
//   59768832   cs      fp32    393216   (legacy: c state | persist: barU counters)
//   60162048   h0      bf16    196608
//   60358656   h1      bf16    196608
//   60555264   smallC  fp32     32768
//   60588032   bar     int       8192   (unused in persist path)
//   60596224   G       fp32 402653184 | bf16 201326592   (layout [t][128][3072])

#define NB 128
#define LSEQ 256
#define LH 768
#define BGR 32768
#define NWG 96     // legacy path
#define PWG 192    // persistent path: 96 col-groups x 2 row-groups

typedef __attribute__((ext_vector_type(8))) short short8;
typedef __attribute__((ext_vector_type(4))) float floatx4;
typedef __attribute__((ext_vector_type(4))) unsigned int uint4v;
typedef __attribute__((ext_vector_type(2))) unsigned int uint2v;

union frag16 { uint4v u; short8 s; };
union bfbits { __hip_bfloat16 h; unsigned short s; };
union uf2 { uint2v u; float f[2]; };

// fast sigmoid/tanh: v_exp_f32 (2^x) + v_rcp_f32 (harness-validated R4/R7/R8)
__device__ __forceinline__ float fsig(float x) {
    return __builtin_amdgcn_rcpf(1.f + __builtin_amdgcn_exp2f(-1.44269504f * x));
}
__device__ __forceinline__ float ftanhf(float x) {
    return 1.f - 2.f * __builtin_amdgcn_rcpf(1.f + __builtin_amdgcn_exp2f(2.88539008f * x));
}

__device__ __forceinline__ float bf16bits_to_f(unsigned short s) {
    unsigned u = ((unsigned)s) << 16;
    float f;
    __builtin_memcpy(&f, &u, 4);
    return f;
}

// 8 MALL-coherent 16B loads at base + {0..448}
__device__ __forceinline__ void issue8(uint4v* b, const char* base) {
    asm volatile("global_load_dwordx4 %0, %1, off sc0 sc1"            : "=v"(b[0]) : "v"(base));
    asm volatile("global_load_dwordx4 %0, %1, off offset:64 sc0 sc1"  : "=v"(b[1]) : "v"(base));
    asm volatile("global_load_dwordx4 %0, %1, off offset:128 sc0 sc1" : "=v"(b[2]) : "v"(base));
    asm volatile("global_load_dwordx4 %0, %1, off offset:192 sc0 sc1" : "=v"(b[3]) : "v"(base));
    asm volatile("global_load_dwordx4 %0, %1, off offset:256 sc0 sc1" : "=v"(b[4]) : "v"(base));
    asm volatile("global_load_dwordx4 %0, %1, off offset:320 sc0 sc1" : "=v"(b[5]) : "v"(base));
    asm volatile("global_load_dwordx4 %0, %1, off offset:384 sc0 sc1" : "=v"(b[6]) : "v"(base));
    asm volatile("global_load_dwordx4 %0, %1, off offset:448 sc0 sc1" : "=v"(b[7]) : "v"(base));
}
// 4 asm 8B loads: gates I,F,G,O for 2 units (byte offsets 0,3072,6144,9216)
__device__ __forceinline__ void issueG2(uint2v* g, const char* gb) {
    const char* gb2 = gb + 6144;
    asm volatile("global_load_dwordx2 %0, %1, off"             : "=v"(g[0]) : "v"(gb));
    asm volatile("global_load_dwordx2 %0, %1, off offset:3072" : "=v"(g[1]) : "v"(gb));
    asm volatile("global_load_dwordx2 %0, %1, off"             : "=v"(g[2]) : "v"(gb2));
    asm volatile("global_load_dwordx2 %0, %1, off offset:3072" : "=v"(g[3]) : "v"(gb2));
}
// counted waits with register ties so consumers cannot be hoisted above them
__device__ __forceinline__ void wait16g_touch(uint4v* b, uint2v* g) {
    asm volatile("s_waitcnt vmcnt(16)"
        : "+v"(b[0]), "+v"(b[1]), "+v"(b[2]), "+v"(b[3]),
          "+v"(b[4]), "+v"(b[5]), "+v"(b[6]), "+v"(b[7]),
          "+v"(g[0]), "+v"(g[1]), "+v"(g[2]), "+v"(g[3]) :: "memory");
}
__device__ __forceinline__ void wait8_touch(uint4v* b) {
    asm volatile("s_waitcnt vmcnt(8)"
        : "+v"(b[0]), "+v"(b[1]), "+v"(b[2]), "+v"(b[3]),
          "+v"(b[4]), "+v"(b[5]), "+v"(b[6]), "+v"(b[7]) :: "memory");
}
__device__ __forceinline__ void wait0_touch(uint4v* b) {
    asm volatile("s_waitcnt vmcnt(0)"
        : "+v"(b[0]), "+v"(b[1]), "+v"(b[2]), "+v"(b[3]),
          "+v"(b[4]), "+v"(b[5]), "+v"(b[6]), "+v"(b[7]) :: "memory");
}

// ---------------- Canonicalize weights (fp32 inputs) ----------------
// smallC: W_pre@0(96) b_pre@96(32) W_gat@128(1024) att_src@1152(32)
//         att_dst@1184(32) b_gat@1216(32) b_ih@1248(3072) b_hh@4320(3072)
__global__ __launch_bounds__(256) void convert_kernel(
    const float* W_pre, const float* b_pre, const float* W_gat,
    const float* att_src, const float* att_dst, const float* b_gat,
    const float* W_ih, const float* W_hh, const float* b_ih, const float* b_hh,
    __hip_bfloat16* __restrict__ WihC, __hip_bfloat16* __restrict__ WhhC,
    float* __restrict__ smallC)
{
    long i = (long)blockIdx.x * 256 + threadIdx.x;
    if (i < 2359296) { WihC[i] = __float2bfloat16(W_ih[i]); return; }
    i -= 2359296;
    if (i < 2359296) { WhhC[i] = __float2bfloat16(W_hh[i]); return; }
    i -= 2359296;
    if (i < 96)   { smallC[0 + i]    = W_pre[i];   return; }  i -= 96;
    if (i < 32)   { smallC[96 + i]   = b_pre[i];   return; }  i -= 32;
    if (i < 1024) { smallC[128 + i]  = W_gat[i];   return; }  i -= 1024;
    if (i < 32)   { smallC[1152 + i] = att_src[i]; return; }  i -= 32;
    if (i < 32)   { smallC[1184 + i] = att_dst[i]; return; }  i -= 32;
    if (i < 32)   { smallC[1216 + i] = b_gat[i];   return; }  i -= 32;
    if (i < 3072) { smallC[1248 + i] = b_ih[i];    return; }  i -= 3072;
    if (i < 3072) { smallC[4320 + i] = b_hh[i];    return; }
}

// ---------------- Kernel A: pre + GAT -> Xb (bf16) ----------------
__global__ __launch_bounds__(256) void gat_pre_kernel(
    const float* __restrict__ src,           // [32768][72]
    const float* __restrict__ smallC,
    __hip_bfloat16* __restrict__ Xb)         // [32768][768]
{
    __shared__ float wpre[96];
    __shared__ float bpre[32];
    __shared__ float wgat[1024];
    __shared__ float asrc[32];
    __shared__ float adst[32];
    __shared__ float bgat[32];
    __shared__ float xl[8][72];
    __shared__ float hl[8][24][32];
    __shared__ float xpl[8][24][32];
    __shared__ float asl[8][24];
    __shared__ float adl[8][24];

    const int tid = threadIdx.x;
    for (int i = tid; i < 96; i += 256)   wpre[i] = smallC[i];
    for (int i = tid; i < 1024; i += 256) wgat[i] = smallC[128 + i];
    if (tid < 32) {
        bpre[tid] = smallC[96 + tid];
        asrc[tid] = smallC[1152 + tid];
        adst[tid] = smallC[1184 + tid];
        bgat[tid] = smallC[1216 + tid];
    }

    const int g = tid >> 5;
    const int k = tid & 31;
    const long gb = (long)blockIdx.x * 8 + g;   // graph id = n*256 + t

    for (int i = k; i < 72; i += 32)
        xl[g][i] = src[gb * 72 + i];
    __syncthreads();

    #pragma unroll
    for (int j = 0; j < 24; ++j) {
        float v = xl[g][j*3+0] * wpre[0*32+k]
                + xl[g][j*3+1] * wpre[1*32+k]
                + xl[g][j*3+2] * wpre[2*32+k] + bpre[k];
        hl[g][j][k] = tanhf(v);
    }
    __syncthreads();

    #pragma unroll
    for (int j = 0; j < 24; ++j) {
        float v = 0.f;
        #pragma unroll
        for (int m = 0; m < 32; ++m) v += hl[g][j][m] * wgat[m*32 + k];
        xpl[g][j][k] = v;
    }
    __syncthreads();

    if (k < 24) {
        float vs = 0.f, vd = 0.f;
        #pragma unroll
        for (int m = 0; m < 32; ++m) {
            float x = xpl[g][k][m];
            vs += x * asrc[m];
            vd += x * adst[m];
        }
        asl[g][k] = vs;
        adl[g][k] = vd;
    }
    __syncthreads();

    const int par[24] = {-1,0,0,0,1,2,3,4,5,6,7,8,9,9,9,12,13,14,16,17,18,19,20,21};
    #pragma unroll
    for (int j = 0; j < 24; ++j) {
        int p = par[j];
        float o;
        if (p < 0) {
            o = xpl[g][j][k] + bgat[k];
        } else {
            float es = adl[g][j] + asl[g][j];
            float ep = adl[g][j] + asl[g][p];
            es = es > 0.f ? es : 0.2f * es;
            ep = ep > 0.f ? ep : 0.2f * ep;
            float mx = fmaxf(es, ep);
            float wse = expf(es - mx), wpe = expf(ep - mx);
            float inv = 1.f / (wse + wpe);
            o = (wse * xpl[g][j][k] + wpe * xpl[g][p][k]) * inv + bgat[k];
        }
        Xb[gb * 768 + j * 32 + k] = __float2bfloat16(o);
    }
}

// ---------------- gates_in v2: G = X @ Wih^T + (b_ih+b_hh), 128x128 tiles ----------------
// grid (256, 24): bx = M-block (rows m*256+t of Xb), by = N-block (wrows).
// G layout [t][128][3072].
__global__ __launch_bounds__(256) void gates_in_kernel(
    const __hip_bfloat16* __restrict__ Xb,   // [32768][768]
    const __hip_bfloat16* __restrict__ Wih,  // [3072][768]
    const float* __restrict__ smallC,
    float* __restrict__ Gf, __hip_bfloat16* __restrict__ Gb, int ginf)
{
    const int tid = threadIdx.x;
    const int w = tid >> 6, L = tid & 63;
    const int rh2 = w >> 1, ch2 = w & 1;
    const int q = L >> 4, col16 = L & 15;
    const int R0 = blockIdx.x * 128;
    const int N0 = blockIdx.y * 128;

    const short8* ap[4];
    const short8* bp[4];
    #pragma unroll
    for (int i = 0; i < 4; ++i) {
        ap[i] = (const short8*)(Xb + (size_t)(R0 + 64*rh2 + 16*i + col16) * 768 + q*8);
        bp[i] = (const short8*)(Wih + (size_t)(N0 + 64*ch2 + 16*i + col16) * 768 + q*8);
    }

    floatx4 acc[4][4] = {};
    for (int kk = 0; kk < 24; ++kk) {
        short8 a[4], b[4];
        #pragma unroll
        for (int i = 0; i < 4; ++i) { a[i] = ap[i][kk*4]; b[i] = bp[i][kk*4]; }
        #pragma unroll
        for (int rt = 0; rt < 4; ++rt)
            #pragma unroll
            for (int bt = 0; bt < 4; ++bt)
                acc[rt][bt] = __builtin_amdgcn_mfma_f32_16x16x32_bf16(a[rt], b[bt], acc[rt][bt], 0, 0, 0);
    }

    #pragma unroll
    for (int bt = 0; bt < 4; ++bt) {
        int wrow = N0 + 64*ch2 + 16*bt + col16;
        float bias = smallC[1248 + wrow] + smallC[4320 + wrow];
        #pragma unroll
        for (int rt = 0; rt < 4; ++rt) {
            #pragma unroll
            for (int r = 0; r < 4; ++r) {
                int m_abs = R0 + 64*rh2 + 16*rt + q*4 + r;   // = m*256 + t
                int mm = m_abs >> 8, tt = m_abs & 255;
                size_t idx = ((size_t)tt * 128 + mm) * 3072 + wrow;
                float v = acc[rt][bt][r] + bias;
                if (ginf) Gf[idx] = v;
                else      Gb[idx] = __float2bfloat16(v);
            }
        }
    }
}

// ---------------- Persistent LSTM: all 256 steps in one launch ----------------
// 192 WGs: cg = bx%96 (units cg*8..+7, 32 gate cols), rg = bx/96 (rows rg*64..+63).
// Wave w = row quarter (16 rows). Whh slice in LDS (blocked, conflict-free).
// h via sc0/sc1 (MALL-coherent). v7: per-row-group barriers (96 WGs each,
// accumulating counters, 8 groups x 12); all 24 h loads issued up front.
__global__ __launch_bounds__(256) void lstm_persist_kernel(
    const void* __restrict__ Gin,             // [t][128][3072] fp32 or bf16
    const __hip_bfloat16* __restrict__ Whh,   // [3072][768]
    __hip_bfloat16* __restrict__ h0g,         // ping-pong h (h0 zeroed)
    __hip_bfloat16* __restrict__ h1g,
    float* __restrict__ out,
    int* __restrict__ barU,                   // accumulating counters, 128B-spaced:
                                              //   L1: [(rg*16+g)*32] g=0..7, L2: [(rg*16+8)*32]
                                              //   epoch: [(rg*16+9)*32]
    int ginf)
{
    __shared__ short8 whhs[3072];             // [kk][c*4+q] 16B fragments, 48 KB
    __shared__ float gl[64 * 33];             // gate staging, 8448 B

    const int tid = threadIdx.x;
    const int w = tid >> 6;                   // row quarter: rows 16w..16w+15 (local)
    const int L = tid & 63;
    const int q = L >> 4;
    const int col16 = L & 15;
    const int cg = blockIdx.x % 96;
    const int rg = blockIdx.x / 96;

    // ---- stage Whh slice into LDS (once): whhs[f], f=(kk<<7)|(c<<2)|q ----
    for (int b = 0; b < 12; ++b) {
        int f = tid + 256 * b;
        int kk = f >> 7, c = (f >> 2) & 31, qq = f & 3;
        int wrow = 768 * (c >> 3) + cg * 8 + (c & 7);
        whhs[f] = *(const short8*)(Whh + (size_t)wrow * 768 + kk * 32 + qq * 8);
    }
    __syncthreads();

    // epilogue assignment: thread -> (row m_loc, unit pair u2b)
    const int m_loc = tid >> 2;               // 0..63
    const int u2b = (tid & 3) * 2;            // 0,2,4,6
    const int m_glob = rg * 64 + m_loc;
    float creg0 = 0.f, creg1 = 0.f;

    const float* Gf = (const float*)Gin;
    const __hip_bfloat16* Gb = (const __hip_bfloat16*)Gin;
    const size_t gcol = cg * 8 + u2b;

    int* myL1    = &barU[(rg * 16 + (cg & 7)) * 32];
    int* myL2    = &barU[(rg * 16 + 8) * 32];
    int* myEpoch = &barU[(rg * 16 + 9) * 32];

    // ---- G[0] asm prefetch (fp32 path): queue [G x4] at loop entry ----
    uint2v gp[4] = {};
    if (ginf)
        issueG2(gp, (const char*)(Gf + (size_t)m_glob * 3072 + gcol));

    for (int t = 0; t < LSEQ; ++t) {
        const char* hr = (const char*)((t & 1) ? h1g : h0g);
        __hip_bfloat16* hw = (t & 1) ? h0g : h1g;

        // ---- recurrent GEMM: A = h rows (16 per wave) from MALL, B = Whh from LDS ----
        // steady-state queue at entry: [out x1, G x4]; issue all 24 h loads.
        // vmcnt(16) retires [out, G x4, bufA x8] — G regs tied here.
        floatx4 acc0 = {}, acc1 = {};
        uint4v bufA[8], bufB[8], bufC[8];
        const char* hbase = hr + (size_t)(((rg * 64 + 16 * w + col16) * 768) + q * 8) * 2;

        issue8(bufA, hbase);
        issue8(bufB, hbase + 512);
        issue8(bufC, hbase + 1024);

        wait16g_touch(bufA, gp);
        #pragma unroll
        for (int j = 0; j < 8; ++j) {
            frag16 fu; fu.u = bufA[j];
            short8 bv0 = whhs[j * 128 + (col16 * 4 + q)];
            short8 bv1 = whhs[j * 128 + ((16 + col16) * 4 + q)];
            acc0 = __builtin_amdgcn_mfma_f32_16x16x32_bf16(fu.s, bv0, acc0, 0, 0, 0);
            acc1 = __builtin_amdgcn_mfma_f32_16x16x32_bf16(fu.s, bv1, acc1, 0, 0, 0);
        }
        wait8_touch(bufB);
        #pragma unroll
        for (int j = 0; j < 8; ++j) {
            frag16 fu; fu.u = bufB[j];
            short8 bv0 = whhs[(8 + j) * 128 + (col16 * 4 + q)];
            short8 bv1 = whhs[(8 + j) * 128 + ((16 + col16) * 4 + q)];
            acc0 = __builtin_amdgcn_mfma_f32_16x16x32_bf16(fu.s, bv0, acc0, 0, 0, 0);
            acc1 = __builtin_amdgcn_mfma_f32_16x16x32_bf16(fu.s, bv1, acc1, 0, 0, 0);
        }
        wait0_touch(bufC);
        #pragma unroll
        for (int j = 0; j < 8; ++j) {
            frag16 fu; fu.u = bufC[j];
            short8 bv0 = whhs[(16 + j) * 128 + (col16 * 4 + q)];
            short8 bv1 = whhs[(16 + j) * 128 + ((16 + col16) * 4 + q)];
            acc0 = __builtin_amdgcn_mfma_f32_16x16x32_bf16(fu.s, bv0, acc0, 0, 0, 0);
            acc1 = __builtin_amdgcn_mfma_f32_16x16x32_bf16(fu.s, bv1, acc1, 0, 0, 0);
        }

        // ---- D -> gl: row = 16w + q*4 + r, cols col16 / 16+col16 ----
        #pragma unroll
        for (int r = 0; r < 4; ++r) {
            int mr = 16 * w + q * 4 + r;
            gl[mr * 33 + col16] = acc0[r];
            gl[mr * 33 + 16 + col16] = acc1[r];
        }
        __syncthreads();

        // ---- G values for this step (fp32: from retired asm prefetch regs) ----
        float gI0, gI1, gF0, gF1, gG0, gG1, gO0, gO1;
        if (ginf) {
            uf2 uI, uF, uG, uO;
            uI.u = gp[0]; uF.u = gp[1]; uG.u = gp[2]; uO.u = gp[3];
            gI0 = uI.f[0]; gI1 = uI.f[1]; gF0 = uF.f[0]; gF1 = uF.f[1];
            gG0 = uG.f[0]; gG1 = uG.f[1]; gO0 = uO.f[0]; gO1 = uO.f[1];
        } else {
            const size_t grow = ((size_t)t * 128 + m_glob) * 3072 + gcol;
            unsigned vi = *(const unsigned*)(Gb + grow);
            unsigned vf = *(const unsigned*)(Gb + grow + 768);
            unsigned vg = *(const unsigned*)(Gb + grow + 1536);
            unsigned vo = *(const unsigned*)(Gb + grow + 2304);
            gI0 = bf16bits_to_f(vi & 0xFFFF); gI1 = bf16bits_to_f(vi >> 16);
            gF0 = bf16bits_to_f(vf & 0xFFFF); gF1 = bf16bits_to_f(vf >> 16);
            gG0 = bf16bits_to_f(vg & 0xFFFF); gG1 = bf16bits_to_f(vg >> 16);
            gO0 = bf16bits_to_f(vo & 0xFFFF); gO1 = bf16bits_to_f(vo >> 16);
        }

        // ---- elementwise LSTM update (pair of units per thread) ----
        float ig0 = gI0 + gl[m_loc * 33 + 0  + u2b];
        float fg0 = gF0 + gl[m_loc * 33 + 8  + u2b];
        float gg0 = gG0 + gl[m_loc * 33 + 16 + u2b];
        float og0 = gO0 + gl[m_loc * 33 + 24 + u2b];
        float ig1 = gI1 + gl[m_loc * 33 + 0  + u2b + 1];
        float fg1 = gF1 + gl[m_loc * 33 + 8  + u2b + 1];
        float gg1 = gG1 + gl[m_loc * 33 + 16 + u2b + 1];
        float og1 = gO1 + gl[m_loc * 33 + 24 + u2b + 1];

        float si0 = fsig(ig0), sf0 = fsig(fg0), so0 = fsig(og0);
        float cn0 = sf0 * creg0 + si0 * ftanhf(gg0);
        float hv0 = so0 * ftanhf(cn0);
        creg0 = cn0;
        float si1 = fsig(ig1), sf1 = fsig(fg1), so1 = fsig(og1);
        float cn1 = sf1 * creg1 + si1 * ftanhf(gg1);
        float hv1 = so1 * ftanhf(cn1);
        creg1 = cn1;

        bfbits b0, b1;
        b0.h = __float2bfloat16(hv0);
        b1.h = __float2bfloat16(hv1);
        unsigned hpack = (unsigned)b0.s | ((unsigned)b1.s << 16);
        char* ha = (char*)hw + (size_t)(m_glob * 768 + cg * 8 + u2b) * 2;
        float2 ov; ov.x = hv0; ov.y = hv1;
        float* oa = out + ((size_t)m_glob * 256 + t) * 768 + cg * 8 + u2b;

        if (t < LSEQ - 1) {
            // issue order: h store (oldest) | out store | G[t+1] x4
            // vmcnt(5) retires exactly the h store; out + G drain during barrier.
            asm volatile("global_store_dword %0, %1, off sc0 sc1" :: "v"(ha), "v"(hpack) : "memory");
            asm volatile("global_store_dwordx2 %0, %1, off" :: "v"(oa), "v"(ov) : "memory");
            if (ginf)
                issueG2(gp, (const char*)(Gf + ((size_t)(t + 1) * 128 + m_glob) * 3072 + gcol));
            asm volatile("s_waitcnt vmcnt(5)" ::: "memory");
            __builtin_amdgcn_s_barrier();     // all 4 waves' h stores retired
            if (tid == 0) {
                // per-rg accumulating two-level barrier: 8 groups x 12 WGs
                int prev = __hip_atomic_fetch_add(myL1, 1,
                                                  __ATOMIC_RELAXED, __HIP_MEMORY_SCOPE_AGENT);
                bool rel = false;
                if (prev == 12 * (t + 1) - 1) {                // last of this group, step t
                    int pr = __hip_atomic_fetch_add(myL2, 1,
                                                    __ATOMIC_RELAXED, __HIP_MEMORY_SCOPE_AGENT);
                    if (pr == 8 * (t + 1) - 1) {               // last group of this rg
                        __hip_atomic_store(myEpoch, t + 1,
                                           __ATOMIC_RELAXED, __HIP_MEMORY_SCOPE_AGENT);
                        rel = true;
                    }
                }
                if (!rel) {
                    while (__hip_atomic_load(myEpoch, __ATOMIC_RELAXED,
                                             __HIP_MEMORY_SCOPE_AGENT) < t + 1)
                        __builtin_amdgcn_s_sleep(2);
                }
            }
            __builtin_amdgcn_s_barrier();
        } else {
            asm volatile("global_store_dwordx2 %0, %1, off" :: "v"(oa), "v"(ov) : "memory");
            const size_t base = (size_t)NB * LSEQ * LH;
            const size_t ci = (size_t)m_glob * 768 + cg * 8 + u2b;
            float2 hv; hv.x = hv0; hv.y = hv1;
            float2 cv; cv.x = cn0; cv.y = cn1;
            *(float2*)(out + base + ci) = hv;
            *(float2*)(out + base + (size_t)NB * LH + ci) = cv;
        }
    }
}

// ---------------- Legacy round-3 per-step path (ws fallback, proven) ----------------
__global__ __launch_bounds__(256) void lstm_step_kernel(
    const __hip_bfloat16* __restrict__ Xb,
    const __hip_bfloat16* __restrict__ Wih,
    const __hip_bfloat16* __restrict__ Whh,
    const float* __restrict__ smallC,
    float* __restrict__ cst,
    const __hip_bfloat16* __restrict__ hr,
    __hip_bfloat16* __restrict__ hw,
    float* __restrict__ out,
    int t)
{
    __shared__ float gls[128 * 33];
    const int tid = threadIdx.x;
    const int w = tid >> 6;
    const int L = tid & 63;
    const int rh = w >> 1;
    const int ct = w & 1;
    const int q = L >> 4;
    const int col16 = L & 15;
    const int c_local = 16 * ct + col16;
    const int gate = c_local >> 3;
    const int uu = c_local & 7;
    const int u = 8 * blockIdx.x + uu;
    const int wrow = 768 * gate + u;

    const short8* bp_i = (const short8*)(Wih + (long)wrow * 768 + q * 8);
    const short8* bp_h = (const short8*)(Whh + (long)wrow * 768 + q * 8);
    const short8* ap_x[4];
    const short8* ap_h[4];
    #pragma unroll
    for (int rt = 0; rt < 4; ++rt) {
        int m = 64 * rh + 16 * rt + col16;
        ap_x[rt] = (const short8*)(Xb + ((long)m * LSEQ + t) * 768 + q * 8);
        ap_h[rt] = (const short8*)(hr + (long)m * 768 + q * 8);
    }
    floatx4 acc[4] = {};
    for (int kk = 0; kk < 768; kk += 32) {
        short8 bv = bp_i[kk >> 3];
        #pragma unroll
        for (int rt = 0; rt < 4; ++rt)
            acc[rt] = __builtin_amdgcn_mfma_f32_16x16x32_bf16(ap_x[rt][kk >> 3], bv, acc[rt], 0, 0, 0);
    }
    for (int kk = 0; kk < 768; kk += 32) {
        short8 bv = bp_h[kk >> 3];
        #pragma unroll
        for (int rt = 0; rt < 4; ++rt)
            acc[rt] = __builtin_amdgcn_mfma_f32_16x16x32_bf16(ap_h[rt][kk >> 3], bv, acc[rt], 0, 0, 0);
    }
    float bias = smallC[1248 + wrow] + smallC[4320 + wrow];
    #pragma unroll
    for (int rt = 0; rt < 4; ++rt)
        #pragma unroll
        for (int r = 0; r < 4; ++r) {
            int m = 64 * rh + 16 * rt + q * 4 + r;
            gls[m * 33 + c_local] = acc[rt][r] + bias;
        }
    __syncthreads();
    for (int item = tid; item < 1024; item += 256) {
        int m = item >> 3;
        int u2l = item & 7;
        float ig = gls[m * 33 + 0  + u2l];
        float fg = gls[m * 33 + 8  + u2l];
        float gg = gls[m * 33 + 16 + u2l];
        float og = gls[m * 33 + 24 + u2l];
        int u2 = 8 * blockIdx.x + u2l;
        int ci = m * 768 + u2;
        float co = cst[ci];
        float si = 1.f / (1.f + expf(-ig));
        float sf = 1.f / (1.f + expf(-fg));
        float so = 1.f / (1.f + expf(-og));
        float cn = sf * co + si * tanhf(gg);
        float h = so * tanhf(cn);
        cst[ci] = cn;
        hw[ci] = __float2bfloat16(h);
        out[((long)m * LSEQ + t) * 768 + u2] = h;
    }
}

__global__ __launch_bounds__(256) void finalize_kernel(
    const __hip_bfloat16* __restrict__ hfin,
    const float* __restrict__ cst,
    float* __restrict__ out)
{
    int i = blockIdx.x * 256 + threadIdx.x;
    const long base = (long)NB * LSEQ * LH;
    out[base + i] = __bfloat162float(hfin[i]);
    out[base + NB * LH + i] = cst[i];
}

extern "C" void kernel_launch(void* const* d_in, const int* in_sizes, int n_in,
                              void* d_out, int out_size, void* d_ws, size_t ws_size,
                              hipStream_t stream) {
    const float* src     = (const float*)d_in[0];
    const float* W_pre   = (const float*)d_in[1];
    const float* b_pre   = (const float*)d_in[2];
    const float* W_gat   = (const float*)d_in[3];
    const float* att_src = (const float*)d_in[4];
    const float* att_dst = (const float*)d_in[5];
    const float* b_gat   = (const float*)d_in[6];
    const float* W_ih    = (const float*)d_in[7];
    const float* W_hh    = (const float*)d_in[8];
    const float* b_ih    = (const float*)d_in[9];
    const float* b_hh    = (const float*)d_in[10];

    float* out = (float*)d_out;
    char* ws = (char*)d_ws;

    __hip_bfloat16* Xb     = (__hip_bfloat16*)(ws);
    __hip_bfloat16* WihC   = (__hip_bfloat16*)(ws + 50331648);
    __hip_bfloat16* WhhC   = (__hip_bfloat16*)(ws + 55050240);
    float*          cs     = (float*)         (ws + 59768832);
    __hip_bfloat16* h0     = (__hip_bfloat16*)(ws + 60162048);
    __hip_bfloat16* h1     = (__hip_bfloat16*)(ws + 60358656);
    float*          smallC = (float*)         (ws + 60555264);
    void*           Gin    = (void*)          (ws + 60596224);

    const size_t base_need = 60596224;
    const size_t need_f32  = base_need + (size_t)BGR * 3072 * 4;   // ~463 MB
    const size_t need_b16  = base_need + (size_t)BGR * 3072 * 2;   // ~262 MB
    const int use_persist  = (ws_size >= need_b16);
    const int ginf         = (ws_size >= need_f32);

    hipMemsetAsync(h0, 0, NB * LH * sizeof(__hip_bfloat16), stream);

    const long conv_total = 2359296L * 2 + 7392;
    convert_kernel<<<(int)((conv_total + 255) / 256), 256, 0, stream>>>(
        W_pre, b_pre, W_gat, att_src, att_dst, b_gat,
        W_ih, W_hh, b_ih, b_hh, WihC, WhhC, smallC);

    gat_pre_kernel<<<BGR / 8, 256, 0, stream>>>(src, smallC, Xb);

    if (use_persist) {
        hipMemsetAsync(cs, 0, 327680, stream);   // accumulating barrier counters (barU)
        dim3 ggrid(256, 24);
        gates_in_kernel<<<ggrid, 256, 0, stream>>>(Xb, WihC, smallC,
                                                   (float*)Gin, (__hip_bfloat16*)Gin, ginf);
        lstm_persist_kernel<<<PWG, 256, 0, stream>>>(Gin, WhhC, h0, h1, out,
                                                     (int*)cs, ginf);
    } else {
        hipMemsetAsync(cs, 0, NB * LH * sizeof(float), stream);
        __hip_bfloat16* hp[2] = {h0, h1};
        for (int t = 0; t < LSEQ; ++t) {
            lstm_step_kernel<<<NWG, 256, 0, stream>>>(Xb, WihC, WhhC, smallC,
                                                      cs, hp[t & 1], hp[(t + 1) & 1],
                                                      out, t);
        }
        finalize_kernel<<<NB * LH / 256, 256, 0, stream>>>(h0, cs, out);
    }
}

// Round 7
// 2407.226 us; speedup vs baseline: 3.3921x; 1.0181x over previous
//
#include <hip/hip_runtime.h>
#include <hip/hip_bf16.h>

// GraphEncoder: pre-Linear(3->32)+tanh -> GATConv(32->32, skeleton) -> LSTM(768->768, L=256)
// Inputs/outputs fp32. Compute: bf16 MFMA operands, fp32 accum/state.
//
// R10 (v8): v7 base (proven 2450 us total / 1650 us LSTM) + tail optimizations:
//   1. gat_pre: fast tanh/exp via v_exp_f32/v_rcp_f32 (validated numerics).
//   2. gates_in: 4-wide N-block grouping (1D grid) so each A-tile is reused by
//      4 consecutive dispatches while L2/MALL-resident (was: 256-dispatch gap).
//   3. LSTM: s_sleep(1) poll quantum (was 2). Everything else byte-identical.
//
// ws layout (bytes):
//   0          Xb      bf16  50331648
//   50331648   WihC    bf16   4718592
//   55050240   WhhC    bf16   4718592
//   59768832   cs      fp32    393216   (legacy: c state | persist: barU counters)
//   60162048   h0      bf16    196608
//   60358656   h1      bf16    196608
//   60555264   smallC  fp32     32768
//   60588032   bar     int       8192   (unused in persist path)
//   60596224   G       fp32 402653184 | bf16 201326592   (layout [t][128][3072])

#define NB 128
#define LSEQ 256
#define LH 768
#define BGR 32768
#define NWG 96     // legacy path
#define PWG 192    // persistent path: 96 col-groups x 2 row-groups

typedef __attribute__((ext_vector_type(8))) short short8;
typedef __attribute__((ext_vector_type(4))) float floatx4;
typedef __attribute__((ext_vector_type(4))) unsigned int uint4v;
typedef __attribute__((ext_vector_type(2))) unsigned int uint2v;

union frag16 { uint4v u; short8 s; };
union bfbits { __hip_bfloat16 h; unsigned short s; };
union uf2 { uint2v u; float f[2]; };

// fast sigmoid/tanh/exp: v_exp_f32 (2^x) + v_rcp_f32 (harness-validated R4/R7/R8)
__device__ __forceinline__ float fsig(float x) {
    return __builtin_amdgcn_rcpf(1.f + __builtin_amdgcn_exp2f(-1.44269504f * x));
}
__device__ __forceinline__ float ftanhf(float x) {
    return 1.f - 2.f * __builtin_amdgcn_rcpf(1.f + __builtin_amdgcn_exp2f(2.88539008f * x));
}
__device__ __forceinline__ float fexpf(float x) {
    return __builtin_amdgcn_exp2f(1.44269504f * x);
}

__device__ __forceinline__ float bf16bits_to_f(unsigned short s) {
    unsigned u = ((unsigned)s) << 16;
    float f;
    __builtin_memcpy(&f, &u, 4);
    return f;
}

// 8 MALL-coherent 16B loads at base + {0..448}
__device__ __forceinline__ void issue8(uint4v* b, const char* base) {
    asm volatile("global_load_dwordx4 %0, %1, off sc0 sc1"            : "=v"(b[0]) : "v"(base));
    asm volatile("global_load_dwordx4 %0, %1, off offset:64 sc0 sc1"  : "=v"(b[1]) : "v"(base));
    asm volatile("global_load_dwordx4 %0, %1, off offset:128 sc0 sc1" : "=v"(b[2]) : "v"(base));
    asm volatile("global_load_dwordx4 %0, %1, off offset:192 sc0 sc1" : "=v"(b[3]) : "v"(base));
    asm volatile("global_load_dwordx4 %0, %1, off offset:256 sc0 sc1" : "=v"(b[4]) : "v"(base));
    asm volatile("global_load_dwordx4 %0, %1, off offset:320 sc0 sc1" : "=v"(b[5]) : "v"(base));
    asm volatile("global_load_dwordx4 %0, %1, off offset:384 sc0 sc1" : "=v"(b[6]) : "v"(base));
    asm volatile("global_load_dwordx4 %0, %1, off offset:448 sc0 sc1" : "=v"(b[7]) : "v"(base));
}
// 4 asm 8B loads: gates I,F,G,O for 2 units (byte offsets 0,3072,6144,9216)
__device__ __forceinline__ void issueG2(uint2v* g, const char* gb) {
    const char* gb2 = gb + 6144;
    asm volatile("global_load_dwordx2 %0, %1, off"             : "=v"(g[0]) : "v"(gb));
    asm volatile("global_load_dwordx2 %0, %1, off offset:3072" : "=v"(g[1]) : "v"(gb));
    asm volatile("global_load_dwordx2 %0, %1, off"             : "=v"(g[2]) : "v"(gb2));
    asm volatile("global_load_dwordx2 %0, %1, off offset:3072" : "=v"(g[3]) : "v"(gb2));
}
// counted waits with register ties so consumers cannot be hoisted above them
__device__ __forceinline__ void wait16g_touch(uint4v* b, uint2v* g) {
    asm volatile("s_waitcnt vmcnt(16)"
        : "+v"(b[0]), "+v"(b[1]), "+v"(b[2]), "+v"(b[3]),
          "+v"(b[4]), "+v"(b[5]), "+v"(b[6]), "+v"(b[7]),
          "+v"(g[0]), "+v"(g[1]), "+v"(g[2]), "+v"(g[3]) :: "memory");
}
__device__ __forceinline__ void wait8_touch(uint4v* b) {
    asm volatile("s_waitcnt vmcnt(8)"
        : "+v"(b[0]), "+v"(b[1]), "+v"(b[2]), "+v"(b[3]),
          "+v"(b[4]), "+v"(b[5]), "+v"(b[6]), "+v"(b[7]) :: "memory");
}
__device__ __forceinline__ void wait0_touch(uint4v* b) {
    asm volatile("s_waitcnt vmcnt(0)"
        : "+v"(b[0]), "+v"(b[1]), "+v"(b[2]), "+v"(b[3]),
          "+v"(b[4]), "+v"(b[5]), "+v"(b[6]), "+v"(b[7]) :: "memory");
}

// ---------------- Canonicalize weights (fp32 inputs) ----------------
// smallC: W_pre@0(96) b_pre@96(32) W_gat@128(1024) att_src@1152(32)
//         att_dst@1184(32) b_gat@1216(32) b_ih@1248(3072) b_hh@4320(3072)
__global__ __launch_bounds__(256) void convert_kernel(
    const float* W_pre, const float* b_pre, const float* W_gat,
    const float* att_src, const float* att_dst, const float* b_gat,
    const float* W_ih, const float* W_hh, const float* b_ih, const float* b_hh,
    __hip_bfloat16* __restrict__ WihC, __hip_bfloat16* __restrict__ WhhC,
    float* __restrict__ smallC)
{
    long i = (long)blockIdx.x * 256 + threadIdx.x;
    if (i < 2359296) { WihC[i] = __float2bfloat16(W_ih[i]); return; }
    i -= 2359296;
    if (i < 2359296) { WhhC[i] = __float2bfloat16(W_hh[i]); return; }
    i -= 2359296;
    if (i < 96)   { smallC[0 + i]    = W_pre[i];   return; }  i -= 96;
    if (i < 32)   { smallC[96 + i]   = b_pre[i];   return; }  i -= 32;
    if (i < 1024) { smallC[128 + i]  = W_gat[i];   return; }  i -= 1024;
    if (i < 32)   { smallC[1152 + i] = att_src[i]; return; }  i -= 32;
    if (i < 32)   { smallC[1184 + i] = att_dst[i]; return; }  i -= 32;
    if (i < 32)   { smallC[1216 + i] = b_gat[i];   return; }  i -= 32;
    if (i < 3072) { smallC[1248 + i] = b_ih[i];    return; }  i -= 3072;
    if (i < 3072) { smallC[4320 + i] = b_hh[i];    return; }
}

// ---------------- Kernel A: pre + GAT -> Xb (bf16) ----------------
__global__ __launch_bounds__(256) void gat_pre_kernel(
    const float* __restrict__ src,           // [32768][72]
    const float* __restrict__ smallC,
    __hip_bfloat16* __restrict__ Xb)         // [32768][768]
{
    __shared__ float wpre[96];
    __shared__ float bpre[32];
    __shared__ float wgat[1024];
    __shared__ float asrc[32];
    __shared__ float adst[32];
    __shared__ float bgat[32];
    __shared__ float xl[8][72];
    __shared__ float hl[8][24][32];
    __shared__ float xpl[8][24][32];
    __shared__ float asl[8][24];
    __shared__ float adl[8][24];

    const int tid = threadIdx.x;
    for (int i = tid; i < 96; i += 256)   wpre[i] = smallC[i];
    for (int i = tid; i < 1024; i += 256) wgat[i] = smallC[128 + i];
    if (tid < 32) {
        bpre[tid] = smallC[96 + tid];
        asrc[tid] = smallC[1152 + tid];
        adst[tid] = smallC[1184 + tid];
        bgat[tid] = smallC[1216 + tid];
    }

    const int g = tid >> 5;
    const int k = tid & 31;
    const long gb = (long)blockIdx.x * 8 + g;   // graph id = n*256 + t

    for (int i = k; i < 72; i += 32)
        xl[g][i] = src[gb * 72 + i];
    __syncthreads();

    #pragma unroll
    for (int j = 0; j < 24; ++j) {
        float v = xl[g][j*3+0] * wpre[0*32+k]
                + xl[g][j*3+1] * wpre[1*32+k]
                + xl[g][j*3+2] * wpre[2*32+k] + bpre[k];
        hl[g][j][k] = ftanhf(v);
    }
    __syncthreads();

    #pragma unroll
    for (int j = 0; j < 24; ++j) {
        float v = 0.f;
        #pragma unroll
        for (int m = 0; m < 32; ++m) v += hl[g][j][m] * wgat[m*32 + k];
        xpl[g][j][k] = v;
    }
    __syncthreads();

    if (k < 24) {
        float vs = 0.f, vd = 0.f;
        #pragma unroll
        for (int m = 0; m < 32; ++m) {
            float x = xpl[g][k][m];
            vs += x * asrc[m];
            vd += x * adst[m];
        }
        asl[g][k] = vs;
        adl[g][k] = vd;
    }
    __syncthreads();

    const int par[24] = {-1,0,0,0,1,2,3,4,5,6,7,8,9,9,9,12,13,14,16,17,18,19,20,21};
    #pragma unroll
    for (int j = 0; j < 24; ++j) {
        int p = par[j];
        float o;
        if (p < 0) {
            o = xpl[g][j][k] + bgat[k];
        } else {
            float es = adl[g][j] + asl[g][j];
            float ep = adl[g][j] + asl[g][p];
            es = es > 0.f ? es : 0.2f * es;
            ep = ep > 0.f ? ep : 0.2f * ep;
            float mx = fmaxf(es, ep);
            float wse = fexpf(es - mx), wpe = fexpf(ep - mx);
            float inv = __builtin_amdgcn_rcpf(wse + wpe);
            o = (wse * xpl[g][j][k] + wpe * xpl[g][p][k]) * inv + bgat[k];
        }
        Xb[gb * 768 + j * 32 + k] = __float2bfloat16(o);
    }
}

// ---------------- gates_in v3: G = X @ Wih^T + (b_ih+b_hh), 128x128 tiles ----------------
// 1D grid 6144, 4-wide N grouping: bid -> (M-block, N-block) with consecutive ids
// sharing the A-tile (4 N-blocks) for L2/MALL temporal reuse.
// G layout [t][128][3072].
__global__ __launch_bounds__(256) void gates_in_kernel(
    const __hip_bfloat16* __restrict__ Xb,   // [32768][768]
    const __hip_bfloat16* __restrict__ Wih,  // [3072][768]
    const float* __restrict__ smallC,
    float* __restrict__ Gf, __hip_bfloat16* __restrict__ Gb, int ginf)
{
    const int tid = threadIdx.x;
    const int w = tid >> 6, L = tid & 63;
    const int rh2 = w >> 1, ch2 = w & 1;
    const int q = L >> 4, col16 = L & 15;
    const int bid = blockIdx.x;
    const int g2 = bid >> 10;                // 0..5
    const int r2 = bid & 1023;
    const int R0 = (r2 >> 2) * 128;          // M-block 0..255
    const int N0 = ((g2 << 2) | (r2 & 3)) * 128;  // N-block 0..23

    const short8* ap[4];
    const short8* bp[4];
    #pragma unroll
    for (int i = 0; i < 4; ++i) {
        ap[i] = (const short8*)(Xb + (size_t)(R0 + 64*rh2 + 16*i + col16) * 768 + q*8);
        bp[i] = (const short8*)(Wih + (size_t)(N0 + 64*ch2 + 16*i + col16) * 768 + q*8);
    }

    floatx4 acc[4][4] = {};
    for (int kk = 0; kk < 24; ++kk) {
        short8 a[4], b[4];
        #pragma unroll
        for (int i = 0; i < 4; ++i) { a[i] = ap[i][kk*4]; b[i] = bp[i][kk*4]; }
        #pragma unroll
        for (int rt = 0; rt < 4; ++rt)
            #pragma unroll
            for (int bt = 0; bt < 4; ++bt)
                acc[rt][bt] = __builtin_amdgcn_mfma_f32_16x16x32_bf16(a[rt], b[bt], acc[rt][bt], 0, 0, 0);
    }

    #pragma unroll
    for (int bt = 0; bt < 4; ++bt) {
        int wrow = N0 + 64*ch2 + 16*bt + col16;
        float bias = smallC[1248 + wrow] + smallC[4320 + wrow];
        #pragma unroll
        for (int rt = 0; rt < 4; ++rt) {
            #pragma unroll
            for (int r = 0; r < 4; ++r) {
                int m_abs = R0 + 64*rh2 + 16*rt + q*4 + r;   // = m*256 + t
                int mm = m_abs >> 8, tt = m_abs & 255;
                size_t idx = ((size_t)tt * 128 + mm) * 3072 + wrow;
                float v = acc[rt][bt][r] + bias;
                if (ginf) Gf[idx] = v;
                else      Gb[idx] = __float2bfloat16(v);
            }
        }
    }
}

// ---------------- Persistent LSTM: all 256 steps in one launch ----------------
// 192 WGs: cg = bx%96 (units cg*8..+7, 32 gate cols), rg = bx/96 (rows rg*64..+63).
// Wave w = row quarter (16 rows). Whh slice in LDS (blocked, conflict-free).
// h via sc0/sc1 (MALL-coherent). Per-row-group barriers (96 WGs each,
// accumulating counters, 8 groups x 12); all 24 h loads issued up front.
__global__ __launch_bounds__(256) void lstm_persist_kernel(
    const void* __restrict__ Gin,             // [t][128][3072] fp32 or bf16
    const __hip_bfloat16* __restrict__ Whh,   // [3072][768]
    __hip_bfloat16* __restrict__ h0g,         // ping-pong h (h0 zeroed)
    __hip_bfloat16* __restrict__ h1g,
    float* __restrict__ out,
    int* __restrict__ barU,                   // accumulating counters, 128B-spaced:
                                              //   L1: [(rg*16+g)*32] g=0..7, L2: [(rg*16+8)*32]
                                              //   epoch: [(rg*16+9)*32]
    int ginf)
{
    __shared__ short8 whhs[3072];             // [kk][c*4+q] 16B fragments, 48 KB
    __shared__ float gl[64 * 33];             // gate staging, 8448 B

    const int tid = threadIdx.x;
    const int w = tid >> 6;                   // row quarter: rows 16w..16w+15 (local)
    const int L = tid & 63;
    const int q = L >> 4;
    const int col16 = L & 15;
    const int cg = blockIdx.x % 96;
    const int rg = blockIdx.x / 96;

    // ---- stage Whh slice into LDS (once): whhs[f], f=(kk<<7)|(c<<2)|q ----
    for (int b = 0; b < 12; ++b) {
        int f = tid + 256 * b;
        int kk = f >> 7, c = (f >> 2) & 31, qq = f & 3;
        int wrow = 768 * (c >> 3) + cg * 8 + (c & 7);
        whhs[f] = *(const short8*)(Whh + (size_t)wrow * 768 + kk * 32 + qq * 8);
    }
    __syncthreads();

    // epilogue assignment: thread -> (row m_loc, unit pair u2b)
    const int m_loc = tid >> 2;               // 0..63
    const int u2b = (tid & 3) * 2;            // 0,2,4,6
    const int m_glob = rg * 64 + m_loc;
    float creg0 = 0.f, creg1 = 0.f;

    const float* Gf = (const float*)Gin;
    const __hip_bfloat16* Gb = (const __hip_bfloat16*)Gin;
    const size_t gcol = cg * 8 + u2b;

    int* myL1    = &barU[(rg * 16 + (cg & 7)) * 32];
    int* myL2    = &barU[(rg * 16 + 8) * 32];
    int* myEpoch = &barU[(rg * 16 + 9) * 32];

    // ---- G[0] asm prefetch (fp32 path): queue [G x4] at loop entry ----
    uint2v gp[4] = {};
    if (ginf)
        issueG2(gp, (const char*)(Gf + (size_t)m_glob * 3072 + gcol));

    for (int t = 0; t < LSEQ; ++t) {
        const char* hr = (const char*)((t & 1) ? h1g : h0g);
        __hip_bfloat16* hw = (t & 1) ? h0g : h1g;

        // ---- recurrent GEMM: A = h rows (16 per wave) from MALL, B = Whh from LDS ----
        // steady-state queue at entry: [out x1, G x4]; issue all 24 h loads.
        // vmcnt(16) retires [out, G x4, bufA x8] — G regs tied here.
        floatx4 acc0 = {}, acc1 = {};
        uint4v bufA[8], bufB[8], bufC[8];
        const char* hbase = hr + (size_t)(((rg * 64 + 16 * w + col16) * 768) + q * 8) * 2;

        issue8(bufA, hbase);
        issue8(bufB, hbase + 512);
        issue8(bufC, hbase + 1024);

        wait16g_touch(bufA, gp);
        #pragma unroll
        for (int j = 0; j < 8; ++j) {
            frag16 fu; fu.u = bufA[j];
            short8 bv0 = whhs[j * 128 + (col16 * 4 + q)];
            short8 bv1 = whhs[j * 128 + ((16 + col16) * 4 + q)];
            acc0 = __builtin_amdgcn_mfma_f32_16x16x32_bf16(fu.s, bv0, acc0, 0, 0, 0);
            acc1 = __builtin_amdgcn_mfma_f32_16x16x32_bf16(fu.s, bv1, acc1, 0, 0, 0);
        }
        wait8_touch(bufB);
        #pragma unroll
        for (int j = 0; j < 8; ++j) {
            frag16 fu; fu.u = bufB[j];
            short8 bv0 = whhs[(8 + j) * 128 + (col16 * 4 + q)];
            short8 bv1 = whhs[(8 + j) * 128 + ((16 + col16) * 4 + q)];
            acc0 = __builtin_amdgcn_mfma_f32_16x16x32_bf16(fu.s, bv0, acc0, 0, 0, 0);
            acc1 = __builtin_amdgcn_mfma_f32_16x16x32_bf16(fu.s, bv1, acc1, 0, 0, 0);
        }
        wait0_touch(bufC);
        #pragma unroll
        for (int j = 0; j < 8; ++j) {
            frag16 fu; fu.u = bufC[j];
            short8 bv0 = whhs[(16 + j) * 128 + (col16 * 4 + q)];
            short8 bv1 = whhs[(16 + j) * 128 + ((16 + col16) * 4 + q)];
            acc0 = __builtin_amdgcn_mfma_f32_16x16x32_bf16(fu.s, bv0, acc0, 0, 0, 0);
            acc1 = __builtin_amdgcn_mfma_f32_16x16x32_bf16(fu.s, bv1, acc1, 0, 0, 0);
        }

        // ---- D -> gl: row = 16w + q*4 + r, cols col16 / 16+col16 ----
        #pragma unroll
        for (int r = 0; r < 4; ++r) {
            int mr = 16 * w + q * 4 + r;
            gl[mr * 33 + col16] = acc0[r];
            gl[mr * 33 + 16 + col16] = acc1[r];
        }
        __syncthreads();

        // ---- G values for this step (fp32: from retired asm prefetch regs) ----
        float gI0, gI1, gF0, gF1, gG0, gG1, gO0, gO1;
        if (ginf) {
            uf2 uI, uF, uG, uO;
            uI.u = gp[0]; uF.u = gp[1]; uG.u = gp[2]; uO.u = gp[3];
            gI0 = uI.f[0]; gI1 = uI.f[1]; gF0 = uF.f[0]; gF1 = uF.f[1];
            gG0 = uG.f[0]; gG1 = uG.f[1]; gO0 = uO.f[0]; gO1 = uO.f[1];
        } else {
            const size_t grow = ((size_t)t * 128 + m_glob) * 3072 + gcol;
            unsigned vi = *(const unsigned*)(Gb + grow);
            unsigned vf = *(const unsigned*)(Gb + grow + 768);
            unsigned vg = *(const unsigned*)(Gb + grow + 1536);
            unsigned vo = *(const unsigned*)(Gb + grow + 2304);
            gI0 = bf16bits_to_f(vi & 0xFFFF); gI1 = bf16bits_to_f(vi >> 16);
            gF0 = bf16bits_to_f(vf & 0xFFFF); gF1 = bf16bits_to_f(vf >> 16);
            gG0 = bf16bits_to_f(vg & 0xFFFF); gG1 = bf16bits_to_f(vg >> 16);
            gO0 = bf16bits_to_f(vo & 0xFFFF); gO1 = bf16bits_to_f(vo >> 16);
        }

        // ---- elementwise LSTM update (pair of units per thread) ----
        float ig0 = gI0 + gl[m_loc * 33 + 0  + u2b];
        float fg0 = gF0 + gl[m_loc * 33 + 8  + u2b];
        float gg0 = gG0 + gl[m_loc * 33 + 16 + u2b];
        float og0 = gO0 + gl[m_loc * 33 + 24 + u2b];
        float ig1 = gI1 + gl[m_loc * 33 + 0  + u2b + 1];
        float fg1 = gF1 + gl[m_loc * 33 + 8  + u2b + 1];
        float gg1 = gG1 + gl[m_loc * 33 + 16 + u2b + 1];
        float og1 = gO1 + gl[m_loc * 33 + 24 + u2b + 1];

        float si0 = fsig(ig0), sf0 = fsig(fg0), so0 = fsig(og0);
        float cn0 = sf0 * creg0 + si0 * ftanhf(gg0);
        float hv0 = so0 * ftanhf(cn0);
        creg0 = cn0;
        float si1 = fsig(ig1), sf1 = fsig(fg1), so1 = fsig(og1);
        float cn1 = sf1 * creg1 + si1 * ftanhf(gg1);
        float hv1 = so1 * ftanhf(cn1);
        creg1 = cn1;

        bfbits b0, b1;
        b0.h = __float2bfloat16(hv0);
        b1.h = __float2bfloat16(hv1);
        unsigned hpack = (unsigned)b0.s | ((unsigned)b1.s << 16);
        char* ha = (char*)hw + (size_t)(m_glob * 768 + cg * 8 + u2b) * 2;
        float2 ov; ov.x = hv0; ov.y = hv1;
        float* oa = out + ((size_t)m_glob * 256 + t) * 768 + cg * 8 + u2b;

        if (t < LSEQ - 1) {
            // issue order: h store (oldest) | out store | G[t+1] x4
            // vmcnt(5) retires exactly the h store; out + G drain during barrier.
            asm volatile("global_store_dword %0, %1, off sc0 sc1" :: "v"(ha), "v"(hpack) : "memory");
            asm volatile("global_store_dwordx2 %0, %1, off" :: "v"(oa), "v"(ov) : "memory");
            if (ginf)
                issueG2(gp, (const char*)(Gf + ((size_t)(t + 1) * 128 + m_glob) * 3072 + gcol));
            asm volatile("s_waitcnt vmcnt(5)" ::: "memory");
            __builtin_amdgcn_s_barrier();     // all 4 waves' h stores retired
            if (tid == 0) {
                // per-rg accumulating two-level barrier: 8 groups x 12 WGs
                int prev = __hip_atomic_fetch_add(myL1, 1,
                                                  __ATOMIC_RELAXED, __HIP_MEMORY_SCOPE_AGENT);
                bool rel = false;
                if (prev == 12 * (t + 1) - 1) {                // last of this group, step t
                    int pr = __hip_atomic_fetch_add(myL2, 1,
                                                    __ATOMIC_RELAXED, __HIP_MEMORY_SCOPE_AGENT);
                    if (pr == 8 * (t + 1) - 1) {               // last group of this rg
                        __hip_atomic_store(myEpoch, t + 1,
                                           __ATOMIC_RELAXED, __HIP_MEMORY_SCOPE_AGENT);
                        rel = true;
                    }
                }
                if (!rel) {
                    while (__hip_atomic_load(myEpoch, __ATOMIC_RELAXED,
                                             __HIP_MEMORY_SCOPE_AGENT) < t + 1)
                        __builtin_amdgcn_s_sleep(1);
                }
            }
            __builtin_amdgcn_s_barrier();
        } else {
            asm volatile("global_store_dwordx2 %0, %1, off" :: "v"(oa), "v"(ov) : "memory");
            const size_t base = (size_t)NB * LSEQ * LH;
            const size_t ci = (size_t)m_glob * 768 + cg * 8 + u2b;
            float2 hv; hv.x = hv0; hv.y = hv1;
            float2 cv; cv.x = cn0; cv.y = cn1;
            *(float2*)(out + base + ci) = hv;
            *(float2*)(out + base + (size_t)NB * LH + ci) = cv;
        }
    }
}

// ---------------- Legacy round-3 per-step path (ws fallback, proven) ----------------
__global__ __launch_bounds__(256) void lstm_step_kernel(
    const __hip_bfloat16* __restrict__ Xb,
    const __hip_bfloat16* __restrict__ Wih,
    const __hip_bfloat16* __restrict__ Whh,
    const float* __restrict__ smallC,
    float* __restrict__ cst,
    const __hip_bfloat16* __restrict__ hr,
    __hip_bfloat16* __restrict__ hw,
    float* __restrict__ out,
    int t)
{
    __shared__ float gls[128 * 33];
    const int tid = threadIdx.x;
    const int w = tid >> 6;
    const int L = tid & 63;
    const int rh = w >> 1;
    const int ct = w & 1;
    const int q = L >> 4;
    const int col16 = L & 15;
    const int c_local = 16 * ct + col16;
    const int gate = c_local >> 3;
    const int uu = c_local & 7;
    const int u = 8 * blockIdx.x + uu;
    const int wrow = 768 * gate + u;

    const short8* bp_i = (const short8*)(Wih + (long)wrow * 768 + q * 8);
    const short8* bp_h = (const short8*)(Whh + (long)wrow * 768 + q * 8);
    const short8* ap_x[4];
    const short8* ap_h[4];
    #pragma unroll
    for (int rt = 0; rt < 4; ++rt) {
        int m = 64 * rh + 16 * rt + col16;
        ap_x[rt] = (const short8*)(Xb + ((long)m * LSEQ + t) * 768 + q * 8);
        ap_h[rt] = (const short8*)(hr + (long)m * 768 + q * 8);
    }
    floatx4 acc[4] = {};
    for (int kk = 0; kk < 768; kk += 32) {
        short8 bv = bp_i[kk >> 3];
        #pragma unroll
        for (int rt = 0; rt < 4; ++rt)
            acc[rt] = __builtin_amdgcn_mfma_f32_16x16x32_bf16(ap_x[rt][kk >> 3], bv, acc[rt], 0, 0, 0);
    }
    for (int kk = 0; kk < 768; kk += 32) {
        short8 bv = bp_h[kk >> 3];
        #pragma unroll
        for (int rt = 0; rt < 4; ++rt)
            acc[rt] = __builtin_amdgcn_mfma_f32_16x16x32_bf16(ap_h[rt][kk >> 3], bv, acc[rt], 0, 0, 0);
    }
    float bias = smallC[1248 + wrow] + smallC[4320 + wrow];
    #pragma unroll
    for (int rt = 0; rt < 4; ++rt)
        #pragma unroll
        for (int r = 0; r < 4; ++r) {
            int m = 64 * rh + 16 * rt + q * 4 + r;
            gls[m * 33 + c_local] = acc[rt][r] + bias;
        }
    __syncthreads();
    for (int item = tid; item < 1024; item += 256) {
        int m = item >> 3;
        int u2l = item & 7;
        float ig = gls[m * 33 + 0  + u2l];
        float fg = gls[m * 33 + 8  + u2l];
        float gg = gls[m * 33 + 16 + u2l];
        float og = gls[m * 33 + 24 + u2l];
        int u2 = 8 * blockIdx.x + u2l;
        int ci = m * 768 + u2;
        float co = cst[ci];
        float si = 1.f / (1.f + expf(-ig));
        float sf = 1.f / (1.f + expf(-fg));
        float so = 1.f / (1.f + expf(-og));
        float cn = sf * co + si * tanhf(gg);
        float h = so * tanhf(cn);
        cst[ci] = cn;
        hw[ci] = __float2bfloat16(h);
        out[((long)m * LSEQ + t) * 768 + u2] = h;
    }
}

__global__ __launch_bounds__(256) void finalize_kernel(
    const __hip_bfloat16* __restrict__ hfin,
    const float* __restrict__ cst,
    float* __restrict__ out)
{
    int i = blockIdx.x * 256 + threadIdx.x;
    const long base = (long)NB * LSEQ * LH;
    out[base + i] = __bfloat162float(hfin[i]);
    out[base + NB * LH + i] = cst[i];
}

extern "C" void kernel_launch(void* const* d_in, const int* in_sizes, int n_in,
                              void* d_out, int out_size, void* d_ws, size_t ws_size,
                              hipStream_t stream) {
    const float* src     = (const float*)d_in[0];
    const float* W_pre   = (const float*)d_in[1];
    const float* b_pre   = (const float*)d_in[2];
    const float* W_gat   = (const float*)d_in[3];
    const float* att_src = (const float*)d_in[4];
    const float* att_dst = (const float*)d_in[5];
    const float* b_gat   = (const float*)d_in[6];
    const float* W_ih    = (const float*)d_in[7];
    const float* W_hh    = (const float*)d_in[8];
    const float* b_ih    = (const float*)d_in[9];
    const float* b_hh    = (const float*)d_in[10];

    float* out = (float*)d_out;
    char* ws = (char*)d_ws;

    __hip_bfloat16* Xb     = (__hip_bfloat16*)(ws);
    __hip_bfloat16* WihC   = (__hip_bfloat16*)(ws + 50331648);
    __hip_bfloat16* WhhC   = (__hip_bfloat16*)(ws + 55050240);
    float*          cs     = (float*)         (ws + 59768832);
    __hip_bfloat16* h0     = (__hip_bfloat16*)(ws + 60162048);
    __hip_bfloat16* h1     = (__hip_bfloat16*)(ws + 60358656);
    float*          smallC = (float*)         (ws + 60555264);
    void*           Gin    = (void*)          (ws + 60596224);

    const size_t base_need = 60596224;
    const size_t need_f32  = base_need + (size_t)BGR * 3072 * 4;   // ~463 MB
    const size_t need_b16  = base_need + (size_t)BGR * 3072 * 2;   // ~262 MB
    const int use_persist  = (ws_size >= need_b16);
    const int ginf         = (ws_size >= need_f32);

    hipMemsetAsync(h0, 0, NB * LH * sizeof(__hip_bfloat16), stream);

    const long conv_total = 2359296L * 2 + 7392;
    convert_kernel<<<(int)((conv_total + 255) / 256), 256, 0, stream>>>(
        W_pre, b_pre, W_gat, att_src, att_dst, b_gat,
        W_ih, W_hh, b_ih, b_hh, WihC, WhhC, smallC);

    gat_pre_kernel<<<BGR / 8, 256, 0, stream>>>(src, smallC, Xb);

    if (use_persist) {
        hipMemsetAsync(cs, 0, 327680, stream);   // accumulating barrier counters (barU)
        gates_in_kernel<<<6144, 256, 0, stream>>>(Xb, WihC, smallC,
                                                  (float*)Gin, (__hip_bfloat16*)Gin, ginf);
        lstm_persist_kernel<<<PWG, 256, 0, stream>>>(Gin, WhhC, h0, h1, out,
                                                     (int*)cs, ginf);
    } else {
        hipMemsetAsync(cs, 0, NB * LH * sizeof(float), stream);
        __hip_bfloat16* hp[2] = {h0, h1};
        for (int t = 0; t < LSEQ; ++t) {
            lstm_step_kernel<<<NWG, 256, 0, stream>>>(Xb, WihC, WhhC, smallC,
                                                      cs, hp[t & 1], hp[(t + 1) & 1],
                                                      out, t);
        }
        finalize_kernel<<<NB * LH / 256, 256, 0, stream>>>(h0, cs, out);
    }
}